// Round 3
// baseline (19626.797 us; speedup 1.0000x reference)
//
#include <hip/hip_runtime.h>
#include <hip/hip_bf16.h>

// Per-sample slot stride (floats): padded SAME buffer 32ch x 146 x 20
#define REG 93440

// ---------------------------------------------------------------------------
// Weight repack: [co][ci][kh][kw] -> [ci][k][co] with BN scale folded in.
// Also emits per-channel shift t[co] = (b-m)*s + be,  s = g*rsqrt(v+eps).
// ---------------------------------------------------------------------------
__global__ void repack_k(const float* __restrict__ W, const float* __restrict__ bb,
                         const float* __restrict__ gg, const float* __restrict__ be,
                         const float* __restrict__ mm, const float* __restrict__ vv,
                         float* __restrict__ wOut, float* __restrict__ tOut,
                         int CIN, int KHW, int COUT)
{
    int gid = blockIdx.x * 256 + threadIdx.x;
    if (gid < COUT) {
        float s = gg[gid] * rsqrtf(vv[gid] + 1e-5f);
        tOut[gid] = (bb[gid] - mm[gid]) * s + be[gid];
    }
    int tot = CIN * KHW * COUT;
    if (gid >= tot) return;
    int co = gid % COUT;
    int rest = gid / COUT;       // ci*KHW + k
    int k = rest % KHW;
    int ci = rest / KHW;
    float s = gg[co] * rsqrtf(vv[co] + 1e-5f);
    wOut[gid] = W[(co * CIN + ci) * KHW + k] * s;
}

// ---------------------------------------------------------------------------
// Zero the pad rings of both padded ping-pong buffers (rows 0/145 full width,
// cols 0 and 16 for rows 1..144), per sample, per 32 channels.
// ---------------------------------------------------------------------------
__global__ void zero_rings_k(float* __restrict__ bufA, float* __restrict__ bufB, int cn)
{
    int gid = blockIdx.x * 256 + threadIdx.x;
    int tot = cn * 2 * 32 * 328;
    if (gid >= tot) return;
    int e = gid % 328;
    int rest = gid / 328;
    int ch = rest % 32; rest /= 32;
    int bsel = rest & 1;
    int nl = rest >> 1;
    float* base = (bsel ? bufB : bufA) + (size_t)nl * REG + ch * 2920;
    int row, col;
    if (e < 40) { row = (e < 20) ? 0 : 145; col = (e < 20) ? e : e - 20; }
    else { int e2 = e - 40; row = 1 + (e2 >> 1); col = (e2 & 1) ? 16 : 0; }
    base[row * 20 + col] = 0.f;
}

// ---------------------------------------------------------------------------
// Conv1: 1 -> 32 channels, 3x3 SAME, input built on the fly from x windows.
// out is the padded (32,146,20) buffer.
// NOTE: two distinct zero paddings on the window axis: (a) conv SAME padding
// at window cols -1 and 15 (must be zero ALWAYS), (b) the T-padding baked
// into window extraction (zero when t+c-7 outside [0,108)). Check both.
// ---------------------------------------------------------------------------
__global__ __launch_bounds__(256) void conv1_k(
    const float* __restrict__ x, float* __restrict__ out,
    const float* __restrict__ wr, const float* __restrict__ tv,
    int c0, int cn)
{
    int gid = blockIdx.x * 256 + threadIdx.x;
    if (gid >= cn * 2160) return;
    int nl = gid / 2160, p = gid - nl * 2160;
    int f = p / 15, w = p - f * 15;
    int n = c0 + nl;
    int b = n / 108, t = n - b * 108;

    float acc[32];
#pragma unroll
    for (int i = 0; i < 32; ++i) acc[i] = 0.f;

    for (int kh = 0; kh < 3; ++kh) {
        int ff = f + kh - 1;
        if (ff < 0 || ff >= 144) continue;
        for (int kw = 0; kw < 3; ++kw) {
            int c = w + kw - 1;               // window column
            if (c < 0 || c >= 15) continue;   // conv SAME pad -> zero
            int tt = t + c - 7;
            if (tt < 0 || tt >= 108) continue; // window T-pad -> zero
            float xval = x[(b * 108 + tt) * 144 + ff];
            const float* wp = wr + (kh * 3 + kw) * 32;
#pragma unroll
            for (int q = 0; q < 8; ++q) {
                float4 wv = *(const float4*)(wp + q * 4);
                acc[q * 4 + 0] = fmaf(xval, wv.x, acc[q * 4 + 0]);
                acc[q * 4 + 1] = fmaf(xval, wv.y, acc[q * 4 + 1]);
                acc[q * 4 + 2] = fmaf(xval, wv.z, acc[q * 4 + 2]);
                acc[q * 4 + 3] = fmaf(xval, wv.w, acc[q * 4 + 3]);
            }
        }
    }
    float* ob = out + (size_t)nl * REG + (f + 1) * 20 + (w + 1);
#pragma unroll
    for (int co = 0; co < 32; ++co)
        ob[co * 2920] = fmaxf(acc[co] + tv[co], 0.f);
}

// ---------------------------------------------------------------------------
// Generic 3x3 conv (+optional fused 2x1 maxpool over rows).
// Thread micro-tile: 8 cout x 8 adjacent cols (w0 in {0,8}), one row.
// Aligned float4 loads everywhere. Garbage cols only ever feed masked outputs.
// ---------------------------------------------------------------------------
template<int CIN, int COUT, int IWS, int ICH, int OH, int OW,
         int OIWS, int OCH, int OOFF, int CG, int ROWS, bool POOL>
__global__ __launch_bounds__(CG * 2 * ROWS) void convk(
    const float* __restrict__ in, float* __restrict__ out,
    const float* __restrict__ wr, const float* __restrict__ tv)
{
    constexpr int CGS = (CG == 4) ? 2 : 3;
    const int tid = threadIdx.x;
    const int cg = tid & (CG - 1);
    const int wh = (tid >> CGS) & 1;
    const int row = tid >> (CGS + 1);
    const int r = blockIdx.x * ROWS + row;
    const int n = blockIdx.y;
    const int w0 = wh ? 8 : 0;
    const float* inN = in + (size_t)n * REG;

    float acc[8][8];
#pragma unroll
    for (int a = 0; a < 8; ++a)
#pragma unroll
        for (int b2 = 0; b2 < 8; ++b2) acc[a][b2] = 0.f;

    for (int ci = 0; ci < CIN; ++ci) {
        const float* ip = inN + ci * ICH + r * IWS + w0;
#pragma unroll
        for (int kh = 0; kh < 3; ++kh) {
            const float4* p4 = (const float4*)(ip + kh * IWS);
            float4 A = p4[0], Bv = p4[1], Cv = p4[2];
            float xv[12] = {A.x, A.y, A.z, A.w, Bv.x, Bv.y, Bv.z, Bv.w,
                            Cv.x, Cv.y, Cv.z, Cv.w};
            const float* wp = wr + ((ci * 3 + kh) * 3) * COUT + cg * 8;
#pragma unroll
            for (int kw = 0; kw < 3; ++kw) {
                float4 wA = *(const float4*)(wp + kw * COUT);
                float4 wB = *(const float4*)(wp + kw * COUT + 4);
#pragma unroll
                for (int j = 0; j < 8; ++j) {
                    float xx = xv[j + kw];
                    acc[0][j] = fmaf(xx, wA.x, acc[0][j]);
                    acc[1][j] = fmaf(xx, wA.y, acc[1][j]);
                    acc[2][j] = fmaf(xx, wA.z, acc[2][j]);
                    acc[3][j] = fmaf(xx, wA.w, acc[3][j]);
                    acc[4][j] = fmaf(xx, wB.x, acc[4][j]);
                    acc[5][j] = fmaf(xx, wB.y, acc[5][j]);
                    acc[6][j] = fmaf(xx, wB.z, acc[6][j]);
                    acc[7][j] = fmaf(xx, wB.w, acc[7][j]);
                }
            }
        }
    }

    const int orow = POOL ? (r >> 1) : r;
    float* outN = out + (size_t)n * REG;
#pragma unroll
    for (int co = 0; co < 8; ++co) {
        const int coa = cg * 8 + co;
        const float tb = tv[coa];
        float* ob = outN + coa * OCH + (orow + OOFF) * OIWS + (w0 + OOFF);
#pragma unroll
        for (int j = 0; j < 8; ++j) {
            float vv = fmaxf(acc[co][j] + tb, 0.f);
            if (POOL) {
                float o = __shfl_xor(vv, CG * 2);
                vv = fmaxf(vv, o);
            }
            bool st = (r < OH) && (w0 + j < OW);
            if (POOL) st = st && ((r & 1) == 0);
            if (st) ob[j] = vv;
        }
    }
}

// ---------------------------------------------------------------------------
// Conv7: 64 -> 128 channels, 12x9 VALID on (34,11).
// Grid (cn, 4): each block computes one cout-quarter (32 couts) x 69 pos.
// Input staged in LDS in four 16-channel quarters (26 KB -> 6 blocks/CU).
// Thread tile: 8 couts x 2 positions (pg, pg+64) -> 16 accumulators.
// 4 blocks/sample lifts occupancy ~4x vs the R2 one-block-per-sample design
// (which sat at 14% occupancy / 39% VALUBusy, latency-bound on the L2
// weight stream).
// ---------------------------------------------------------------------------
__global__ __launch_bounds__(256) void conv7_k(
    const float* __restrict__ in, float* __restrict__ out,
    const float* __restrict__ wr, const float* __restrict__ tv)
{
    __shared__ __align__(16) float sIn[6528];  // 16ch x 34 x 12
    const int n = blockIdx.x;
    const int q = blockIdx.y;            // cout quarter
    const int tid = threadIdx.x;
    const int cg = tid & 3;              // 4 groups x 8 couts = 32 couts
    const int pg = tid >> 2;             // 0..63
    const int coB = q * 32 + cg * 8;

    // positions pg and pg+64 (second valid only when pg < 5)
    const bool v1 = (pg + 64) < 69;
    const int p1 = v1 ? (pg + 64) : 0;
    const int h0 = pg / 3, w0p = pg - h0 * 3;
    const int h1 = p1 / 3, w1p = p1 - h1 * 3;
    const int base0 = h0 * 12 + w0p;
    const int base1 = h1 * 12 + w1p;

    float acc[2][8];
#pragma unroll
    for (int i = 0; i < 2; ++i)
#pragma unroll
        for (int c = 0; c < 8; ++c) acc[i][c] = 0.f;

    const float4* g4 = (const float4*)(in + (size_t)n * REG);
    for (int quar = 0; quar < 4; ++quar) {
        __syncthreads();
        float4* s4 = (float4*)sIn;
        for (int i = tid; i < 1632; i += 256) s4[i] = g4[quar * 1632 + i];
        __syncthreads();
        for (int cil = 0; cil < 16; ++cil) {
            int ci = quar * 16 + cil;
            const float* sc = sIn + cil * 408;
            const float* wpc = wr + (size_t)ci * 108 * 128 + coB;
            for (int kh = 0; kh < 12; ++kh) {
                const float* sch = sc + kh * 12;
                const float* wph = wpc + kh * 9 * 128;
#pragma unroll
                for (int kw = 0; kw < 9; ++kw) {
                    float4 wA = *(const float4*)(wph + kw * 128);
                    float4 wB = *(const float4*)(wph + kw * 128 + 4);
                    float x0 = sch[base0 + kw];
                    float x1 = sch[base1 + kw];
                    acc[0][0] = fmaf(x0, wA.x, acc[0][0]);
                    acc[0][1] = fmaf(x0, wA.y, acc[0][1]);
                    acc[0][2] = fmaf(x0, wA.z, acc[0][2]);
                    acc[0][3] = fmaf(x0, wA.w, acc[0][3]);
                    acc[0][4] = fmaf(x0, wB.x, acc[0][4]);
                    acc[0][5] = fmaf(x0, wB.y, acc[0][5]);
                    acc[0][6] = fmaf(x0, wB.z, acc[0][6]);
                    acc[0][7] = fmaf(x0, wB.w, acc[0][7]);
                    acc[1][0] = fmaf(x1, wA.x, acc[1][0]);
                    acc[1][1] = fmaf(x1, wA.y, acc[1][1]);
                    acc[1][2] = fmaf(x1, wA.z, acc[1][2]);
                    acc[1][3] = fmaf(x1, wA.w, acc[1][3]);
                    acc[1][4] = fmaf(x1, wB.x, acc[1][4]);
                    acc[1][5] = fmaf(x1, wB.y, acc[1][5]);
                    acc[1][6] = fmaf(x1, wB.z, acc[1][6]);
                    acc[1][7] = fmaf(x1, wB.w, acc[1][7]);
                }
            }
        }
    }

    float* outN = out + (size_t)n * REG;
#pragma unroll
    for (int co = 0; co < 8; ++co) {
        int coa = coB + co;
        float tb = tv[coa];
        outN[coa * 92 + h0 * 4 + w0p] = fmaxf(acc[0][co] + tb, 0.f);
        if (v1)
            outN[coa * 92 + h1 * 4 + w1p] = fmaxf(acc[1][co] + tb, 0.f);
    }
}

// ---------------------------------------------------------------------------
// Spatial mean over the 23x3 positions of h7 (stored 23 x 4, col 3 slack).
// ---------------------------------------------------------------------------
__global__ void mean_k(const float* __restrict__ in, float* __restrict__ outp, int cn)
{
    int gid = blockIdx.x * 256 + threadIdx.x;
    if (gid >= cn * 128) return;
    int nl = gid >> 7, ci = gid & 127;
    const float4* p = (const float4*)(in + (size_t)nl * REG + ci * 92);
    float s = 0.f;
#pragma unroll
    for (int r = 0; r < 23; ++r) { float4 v = p[r]; s += v.x + v.y + v.z; }
    outp[(size_t)nl * REG + ci] = s * (1.f / 69.f);
}

// ---------------------------------------------------------------------------
// logits = b8 + W8(25x128) . pooled  (1x1 conv commuted past the mean)
// ---------------------------------------------------------------------------
__global__ void logits_k(const float* __restrict__ pooled, const float* __restrict__ W8,
                         const float* __restrict__ b8, float* __restrict__ outg,
                         int c0, int cn)
{
    int gid = blockIdx.x * 256 + threadIdx.x;
    if (gid >= cn * 25) return;
    int nl = gid / 25, c = gid - nl * 25;
    const float* pp = pooled + (size_t)nl * REG;
    const float* wp = W8 + c * 128;
    float s = b8[c];
#pragma unroll
    for (int ci = 0; ci < 128; ci += 4) {
        float4 wv = *(const float4*)(wp + ci);
        float4 pv = *(const float4*)(pp + ci);
        s = fmaf(wv.x, pv.x, s);
        s = fmaf(wv.y, pv.y, s);
        s = fmaf(wv.z, pv.z, s);
        s = fmaf(wv.w, pv.w, s);
    }
    outg[(size_t)(c0 + nl) * 25 + c] = s;
}

// ---------------------------------------------------------------------------
extern "C" void kernel_launch(void* const* d_in, const int* in_sizes, int n_in,
                              void* d_out, int out_size, void* d_ws, size_t ws_size,
                              hipStream_t stream)
{
    const float* x = (const float*)d_in[0];
    // labels = d_in[1], unused
    const float* Wl[8]; const float* bl[8]; const float* gl[8];
    const float* bel[8]; const float* ml[8]; const float* vl[8];
    for (int i = 1; i <= 7; ++i) {
        int o = 2 + (i - 1) * 6;
        Wl[i]  = (const float*)d_in[o + 0];
        bl[i]  = (const float*)d_in[o + 1];
        gl[i]  = (const float*)d_in[o + 2];
        bel[i] = (const float*)d_in[o + 3];
        ml[i]  = (const float*)d_in[o + 4];
        vl[i]  = (const float*)d_in[o + 5];
    }
    const float* W8 = (const float*)d_in[44];
    const float* b8 = (const float*)d_in[45];
    float* ws = (float*)d_ws;

    // Workspace layout (float offsets); all 16B aligned.
    float* wr1 = ws + 0;     float* t1 = ws + 288;
    float* wr2 = ws + 320;   float* t2 = ws + 9536;
    float* wr3 = ws + 9568;  float* t3 = ws + 18784;
    float* wr4 = ws + 18816; float* t4 = ws + 28032;
    float* wr5 = ws + 28064; float* t5 = ws + 46496;
    float* wr6 = ws + 46560; float* t6 = ws + 83424;
    float* wr7 = ws + 83488; float* t7 = ws + 968224;
    const size_t WFL = 968384;

    size_t avail_fl = ws_size / 4;
    size_t buf_fl = (avail_fl > WFL) ? (avail_fl - WFL) : 0;
    int Cs = (int)(buf_fl / (2 * (size_t)REG));
    if (Cs < 1) Cs = 1;
    if (Cs > 1728) Cs = 1728;
    float* bufA = ws + WFL;
    float* bufB = bufA + (size_t)Cs * REG;

    auto g1 = [](int t) { return (t + 255) / 256; };

    // Weight repacks (once per call)
    repack_k<<<g1(288),    256, 0, stream>>>(Wl[1], bl[1], gl[1], bel[1], ml[1], vl[1], wr1, t1, 1,  9,  32);
    repack_k<<<g1(9216),   256, 0, stream>>>(Wl[2], bl[2], gl[2], bel[2], ml[2], vl[2], wr2, t2, 32, 9,  32);
    repack_k<<<g1(9216),   256, 0, stream>>>(Wl[3], bl[3], gl[3], bel[3], ml[3], vl[3], wr3, t3, 32, 9,  32);
    repack_k<<<g1(9216),   256, 0, stream>>>(Wl[4], bl[4], gl[4], bel[4], ml[4], vl[4], wr4, t4, 32, 9,  32);
    repack_k<<<g1(18432),  256, 0, stream>>>(Wl[5], bl[5], gl[5], bel[5], ml[5], vl[5], wr5, t5, 32, 9,  64);
    repack_k<<<g1(36864),  256, 0, stream>>>(Wl[6], bl[6], gl[6], bel[6], ml[6], vl[6], wr6, t6, 64, 9,  64);
    repack_k<<<g1(884736), 256, 0, stream>>>(Wl[7], bl[7], gl[7], bel[7], ml[7], vl[7], wr7, t7, 64, 108, 128);

    for (int c0 = 0; c0 < 1728; c0 += Cs) {
        int cn = (1728 - c0 < Cs) ? (1728 - c0) : Cs;
        zero_rings_k<<<g1(cn * 20992), 256, 0, stream>>>(bufA, bufB, cn);
        conv1_k<<<g1(cn * 2160), 256, 0, stream>>>(x, bufA, wr1, t1, c0, cn);
        // L2: 32->32 SAME on padded (146,20) -> padded
        convk<32, 32, 20, 2920, 144, 15, 20, 2920, 1, 4, 24, false>
            <<<dim3(6, cn), 192, 0, stream>>>(bufA, bufB, wr2, t2);
        // L3
        convk<32, 32, 20, 2920, 144, 15, 20, 2920, 1, 4, 24, false>
            <<<dim3(6, cn), 192, 0, stream>>>(bufB, bufA, wr3, t3);
        // L4 + pool -> (32,72,16) tight
        convk<32, 32, 20, 2920, 144, 15, 16, 1152, 0, 4, 24, true>
            <<<dim3(6, cn), 192, 0, stream>>>(bufA, bufB, wr4, t4);
        // L5 VALID: (32,72,16) -> (64,70,16)
        convk<32, 64, 16, 1152, 70, 13, 16, 1120, 0, 8, 16, false>
            <<<dim3(5, cn), 256, 0, stream>>>(bufB, bufA, wr5, t5);
        // L6 VALID + pool: (64,70,16) -> (64,34,12)
        convk<64, 64, 16, 1120, 68, 11, 12, 408, 0, 8, 16, true>
            <<<dim3(5, cn), 256, 0, stream>>>(bufA, bufB, wr6, t6);
        // L7: (64,34,12) -> (128,23,4), 4 blocks/sample (cout quarters)
        conv7_k<<<dim3(cn, 4), 256, 0, stream>>>(bufB, bufA, wr7, t7);
        mean_k<<<g1(cn * 128), 256, 0, stream>>>(bufA, bufB, cn);
        logits_k<<<g1(cn * 25), 256, 0, stream>>>(bufB, W8, b8, (float*)d_out, c0, cn);
    }
}

// Round 4
// 14086.360 us; speedup vs baseline: 1.3933x; 1.3933x over previous
//
#include <hip/hip_runtime.h>
#include <hip/hip_bf16.h>

// Per-sample slot stride (floats): padded SAME buffer 32ch x 146 x 20
#define REG 93440

// ---------------------------------------------------------------------------
// Weight repack: [co][ci][kh][kw] -> [ci][k][co] with BN scale folded in.
// Also emits per-channel shift t[co] = (b-m)*s + be,  s = g*rsqrt(v+eps).
// ---------------------------------------------------------------------------
__global__ void repack_k(const float* __restrict__ W, const float* __restrict__ bb,
                         const float* __restrict__ gg, const float* __restrict__ be,
                         const float* __restrict__ mm, const float* __restrict__ vv,
                         float* __restrict__ wOut, float* __restrict__ tOut,
                         int CIN, int KHW, int COUT)
{
    int gid = blockIdx.x * 256 + threadIdx.x;
    if (gid < COUT) {
        float s = gg[gid] * rsqrtf(vv[gid] + 1e-5f);
        tOut[gid] = (bb[gid] - mm[gid]) * s + be[gid];
    }
    int tot = CIN * KHW * COUT;
    if (gid >= tot) return;
    int co = gid % COUT;
    int rest = gid / COUT;       // ci*KHW + k
    int k = rest % KHW;
    int ci = rest / KHW;
    float s = gg[co] * rsqrtf(vv[co] + 1e-5f);
    wOut[gid] = W[(co * CIN + ci) * KHW + k] * s;
}

// ---------------------------------------------------------------------------
// Zero the pad rings of both padded ping-pong buffers (rows 0/145 full width,
// cols 0 and 16 for rows 1..144), per sample, per 32 channels.
// ---------------------------------------------------------------------------
__global__ void zero_rings_k(float* __restrict__ bufA, float* __restrict__ bufB, int cn)
{
    int gid = blockIdx.x * 256 + threadIdx.x;
    int tot = cn * 2 * 32 * 328;
    if (gid >= tot) return;
    int e = gid % 328;
    int rest = gid / 328;
    int ch = rest % 32; rest /= 32;
    int bsel = rest & 1;
    int nl = rest >> 1;
    float* base = (bsel ? bufB : bufA) + (size_t)nl * REG + ch * 2920;
    int row, col;
    if (e < 40) { row = (e < 20) ? 0 : 145; col = (e < 20) ? e : e - 20; }
    else { int e2 = e - 40; row = 1 + (e2 >> 1); col = (e2 & 1) ? 16 : 0; }
    base[row * 20 + col] = 0.f;
}

// ---------------------------------------------------------------------------
// Conv1: 1 -> 32 channels, 3x3 SAME, input built on the fly from x windows.
// Two distinct zero paddings on the window axis: (a) conv SAME padding at
// window cols -1/15 (always zero), (b) T-padding (zero when t+c-7 outside
// [0,108)). Check both.
// ---------------------------------------------------------------------------
__global__ __launch_bounds__(256) void conv1_k(
    const float* __restrict__ x, float* __restrict__ out,
    const float* __restrict__ wr, const float* __restrict__ tv,
    int c0, int cn)
{
    int gid = blockIdx.x * 256 + threadIdx.x;
    if (gid >= cn * 2160) return;
    int nl = gid / 2160, p = gid - nl * 2160;
    int f = p / 15, w = p - f * 15;
    int n = c0 + nl;
    int b = n / 108, t = n - b * 108;

    float acc[32];
#pragma unroll
    for (int i = 0; i < 32; ++i) acc[i] = 0.f;

    for (int kh = 0; kh < 3; ++kh) {
        int ff = f + kh - 1;
        if (ff < 0 || ff >= 144) continue;
        for (int kw = 0; kw < 3; ++kw) {
            int c = w + kw - 1;               // window column
            if (c < 0 || c >= 15) continue;   // conv SAME pad -> zero
            int tt = t + c - 7;
            if (tt < 0 || tt >= 108) continue; // window T-pad -> zero
            float xval = x[(b * 108 + tt) * 144 + ff];
            const float* wp = wr + (kh * 3 + kw) * 32;
#pragma unroll
            for (int q = 0; q < 8; ++q) {
                float4 wv = *(const float4*)(wp + q * 4);
                acc[q * 4 + 0] = fmaf(xval, wv.x, acc[q * 4 + 0]);
                acc[q * 4 + 1] = fmaf(xval, wv.y, acc[q * 4 + 1]);
                acc[q * 4 + 2] = fmaf(xval, wv.z, acc[q * 4 + 2]);
                acc[q * 4 + 3] = fmaf(xval, wv.w, acc[q * 4 + 3]);
            }
        }
    }
    float* ob = out + (size_t)nl * REG + (f + 1) * 20 + (w + 1);
#pragma unroll
    for (int co = 0; co < 32; ++co)
        ob[co * 2920] = fmaxf(acc[co] + tv[co], 0.f);
}

// ---------------------------------------------------------------------------
// Generic 3x3 conv (+optional fused 2x1 maxpool over rows).
// Thread micro-tile: 8 cout x 8 adjacent cols (w0 in {0,8}), one row.
// Aligned float4 loads everywhere. Garbage cols only ever feed masked outputs.
// ---------------------------------------------------------------------------
template<int CIN, int COUT, int IWS, int ICH, int OH, int OW,
         int OIWS, int OCH, int OOFF, int CG, int ROWS, bool POOL>
__global__ __launch_bounds__(CG * 2 * ROWS) void convk(
    const float* __restrict__ in, float* __restrict__ out,
    const float* __restrict__ wr, const float* __restrict__ tv)
{
    constexpr int CGS = (CG == 4) ? 2 : 3;
    const int tid = threadIdx.x;
    const int cg = tid & (CG - 1);
    const int wh = (tid >> CGS) & 1;
    const int row = tid >> (CGS + 1);
    const int r = blockIdx.x * ROWS + row;
    const int n = blockIdx.y;
    const int w0 = wh ? 8 : 0;
    const float* inN = in + (size_t)n * REG;

    float acc[8][8];
#pragma unroll
    for (int a = 0; a < 8; ++a)
#pragma unroll
        for (int b2 = 0; b2 < 8; ++b2) acc[a][b2] = 0.f;

    for (int ci = 0; ci < CIN; ++ci) {
        const float* ip = inN + ci * ICH + r * IWS + w0;
#pragma unroll
        for (int kh = 0; kh < 3; ++kh) {
            const float4* p4 = (const float4*)(ip + kh * IWS);
            float4 A = p4[0], Bv = p4[1], Cv = p4[2];
            float xv[12] = {A.x, A.y, A.z, A.w, Bv.x, Bv.y, Bv.z, Bv.w,
                            Cv.x, Cv.y, Cv.z, Cv.w};
            const float* wp = wr + ((ci * 3 + kh) * 3) * COUT + cg * 8;
#pragma unroll
            for (int kw = 0; kw < 3; ++kw) {
                float4 wA = *(const float4*)(wp + kw * COUT);
                float4 wB = *(const float4*)(wp + kw * COUT + 4);
#pragma unroll
                for (int j = 0; j < 8; ++j) {
                    float xx = xv[j + kw];
                    acc[0][j] = fmaf(xx, wA.x, acc[0][j]);
                    acc[1][j] = fmaf(xx, wA.y, acc[1][j]);
                    acc[2][j] = fmaf(xx, wA.z, acc[2][j]);
                    acc[3][j] = fmaf(xx, wA.w, acc[3][j]);
                    acc[4][j] = fmaf(xx, wB.x, acc[4][j]);
                    acc[5][j] = fmaf(xx, wB.y, acc[5][j]);
                    acc[6][j] = fmaf(xx, wB.z, acc[6][j]);
                    acc[7][j] = fmaf(xx, wB.w, acc[7][j]);
                }
            }
        }
    }

    const int orow = POOL ? (r >> 1) : r;
    float* outN = out + (size_t)n * REG;
#pragma unroll
    for (int co = 0; co < 8; ++co) {
        const int coa = cg * 8 + co;
        const float tb = tv[coa];
        float* ob = outN + coa * OCH + (orow + OOFF) * OIWS + (w0 + OOFF);
#pragma unroll
        for (int j = 0; j < 8; ++j) {
            float vv = fmaxf(acc[co][j] + tb, 0.f);
            if (POOL) {
                float o = __shfl_xor(vv, CG * 2);
                vv = fmaxf(vv, o);
            }
            bool st = (r < OH) && (w0 + j < OW);
            if (POOL) st = st && ((r & 1) == 0);
            if (st) ob[j] = vv;
        }
    }
}

// ---------------------------------------------------------------------------
// Conv7 partials: 64 -> 128 ch, 12x9 VALID on (34,11), grid (cn, 4).
// blockIdx.y = (position-half << 1) | ci-half. Each block computes ALL 128
// couts (cg = tid&15 -> full sequential 512B weight rows, the pattern that
// kept R2's FETCH_SIZE at 32MB; the R3 cout-split caused 3x HBM over-fetch)
// for 32 ci and 33-36 positions. Partial sums (no bias/relu) -> part buffer.
// LDS: 16-ch quarters, 26KB -> high block residency. 4 blocks/sample lifts
// occupancy vs R2's 1 block/sample (14% occ, latency-bound at VALUBusy 39%).
// ---------------------------------------------------------------------------
__global__ __launch_bounds__(256) void conv7p_k(
    const float* __restrict__ in, float* __restrict__ part,
    const float* __restrict__ wr)
{
    __shared__ __align__(16) float sIn[6528];  // 16ch x 34 x 12
    const int n = blockIdx.x;
    const int ph = blockIdx.y >> 1;      // position half
    const int ch = blockIdx.y & 1;       // ci half
    const int tid = threadIdx.x;
    const int cg = tid & 15, pg = tid >> 4;
    const int pbase = ph * 36;
    const int plen = ph ? 33 : 36;

    int base[3]; bool val[3]; int pos[3];
#pragma unroll
    for (int i = 0; i < 3; ++i) {
        int lp = pg + 16 * i;
        val[i] = lp < plen;
        int p = pbase + (val[i] ? lp : 0);
        pos[i] = p;
        int h = p / 3, w = p - h * 3;
        base[i] = h * 12 + w;
    }
    float acc[3][8];
#pragma unroll
    for (int i = 0; i < 3; ++i)
#pragma unroll
        for (int c = 0; c < 8; ++c) acc[i][c] = 0.f;

    const float4* g4 = (const float4*)(in + (size_t)n * REG);
    for (int quar = 0; quar < 2; ++quar) {
        __syncthreads();
        float4* s4 = (float4*)sIn;
        int qg = ch * 2 + quar;
        for (int i = tid; i < 1632; i += 256) s4[i] = g4[qg * 1632 + i];
        __syncthreads();
        for (int cil = 0; cil < 16; ++cil) {
            int ci = ch * 32 + quar * 16 + cil;
            const float* sc = sIn + cil * 408;
            const float* wpc = wr + (size_t)ci * 13824 + cg * 8;  // 108*128
            for (int kh = 0; kh < 12; ++kh) {
                const float* sch = sc + kh * 12;
                const float* wph = wpc + kh * 1152;  // 9*128
#pragma unroll
                for (int kw = 0; kw < 9; ++kw) {
                    float4 wA = *(const float4*)(wph + kw * 128);
                    float4 wB = *(const float4*)(wph + kw * 128 + 4);
#pragma unroll
                    for (int i = 0; i < 3; ++i) {
                        float xx = sch[base[i] + kw];
                        acc[i][0] = fmaf(xx, wA.x, acc[i][0]);
                        acc[i][1] = fmaf(xx, wA.y, acc[i][1]);
                        acc[i][2] = fmaf(xx, wA.z, acc[i][2]);
                        acc[i][3] = fmaf(xx, wA.w, acc[i][3]);
                        acc[i][4] = fmaf(xx, wB.x, acc[i][4]);
                        acc[i][5] = fmaf(xx, wB.y, acc[i][5]);
                        acc[i][6] = fmaf(xx, wB.z, acc[i][6]);
                        acc[i][7] = fmaf(xx, wB.w, acc[i][7]);
                    }
                }
            }
        }
    }

    // partial layout per sample: [ch][co][72]  (2*128*72 = 18432 floats)
    float* pb = part + (size_t)n * REG + ch * 9216 + (cg * 8) * 72;
#pragma unroll
    for (int i = 0; i < 3; ++i) {
        if (!val[i]) continue;
#pragma unroll
        for (int co = 0; co < 8; ++co)
            pb[co * 72 + pos[i]] = acc[i][co];
    }
}

// ---------------------------------------------------------------------------
// Combine conv7 ci-half partials + bias -> relu -> spatial mean (1/69).
// One thread per (sample, cout). Replaces the old mean_k.
// ---------------------------------------------------------------------------
__global__ void combine_k(const float* __restrict__ part, float* __restrict__ pooled,
                          const float* __restrict__ tv, int cn)
{
    int gid = blockIdx.x * 256 + threadIdx.x;
    if (gid >= cn * 128) return;
    int nl = gid >> 7, co = gid & 127;
    const float* p0 = part + (size_t)nl * REG + co * 72;
    const float* p1 = p0 + 9216;
    float tb = tv[co];
    float s = 0.f;
#pragma unroll
    for (int r = 0; r < 17; ++r) {   // pos 0..67
        float4 a = *(const float4*)(p0 + r * 4);
        float4 b = *(const float4*)(p1 + r * 4);
        s += fmaxf(a.x + b.x + tb, 0.f) + fmaxf(a.y + b.y + tb, 0.f)
           + fmaxf(a.z + b.z + tb, 0.f) + fmaxf(a.w + b.w + tb, 0.f);
    }
    s += fmaxf(p0[68] + p1[68] + tb, 0.f);
    pooled[(size_t)nl * REG + co] = s * (1.f / 69.f);
}

// ---------------------------------------------------------------------------
// logits = b8 + W8(25x128) . pooled  (1x1 conv commuted past the mean)
// ---------------------------------------------------------------------------
__global__ void logits_k(const float* __restrict__ pooled, const float* __restrict__ W8,
                         const float* __restrict__ b8, float* __restrict__ outg,
                         int c0, int cn)
{
    int gid = blockIdx.x * 256 + threadIdx.x;
    if (gid >= cn * 25) return;
    int nl = gid / 25, c = gid - nl * 25;
    const float* pp = pooled + (size_t)nl * REG;
    const float* wp = W8 + c * 128;
    float s = b8[c];
#pragma unroll
    for (int ci = 0; ci < 128; ci += 4) {
        float4 wv = *(const float4*)(wp + ci);
        float4 pv = *(const float4*)(pp + ci);
        s = fmaf(wv.x, pv.x, s);
        s = fmaf(wv.y, pv.y, s);
        s = fmaf(wv.z, pv.z, s);
        s = fmaf(wv.w, pv.w, s);
    }
    outg[(size_t)(c0 + nl) * 25 + c] = s;
}

// ---------------------------------------------------------------------------
extern "C" void kernel_launch(void* const* d_in, const int* in_sizes, int n_in,
                              void* d_out, int out_size, void* d_ws, size_t ws_size,
                              hipStream_t stream)
{
    const float* x = (const float*)d_in[0];
    // labels = d_in[1], unused
    const float* Wl[8]; const float* bl[8]; const float* gl[8];
    const float* bel[8]; const float* ml[8]; const float* vl[8];
    for (int i = 1; i <= 7; ++i) {
        int o = 2 + (i - 1) * 6;
        Wl[i]  = (const float*)d_in[o + 0];
        bl[i]  = (const float*)d_in[o + 1];
        gl[i]  = (const float*)d_in[o + 2];
        bel[i] = (const float*)d_in[o + 3];
        ml[i]  = (const float*)d_in[o + 4];
        vl[i]  = (const float*)d_in[o + 5];
    }
    const float* W8 = (const float*)d_in[44];
    const float* b8 = (const float*)d_in[45];
    float* ws = (float*)d_ws;

    // Workspace layout (float offsets); all 16B aligned.
    float* wr1 = ws + 0;     float* t1 = ws + 288;
    float* wr2 = ws + 320;   float* t2 = ws + 9536;
    float* wr3 = ws + 9568;  float* t3 = ws + 18784;
    float* wr4 = ws + 18816; float* t4 = ws + 28032;
    float* wr5 = ws + 28064; float* t5 = ws + 46496;
    float* wr6 = ws + 46560; float* t6 = ws + 83424;
    float* wr7 = ws + 83488; float* t7 = ws + 968224;
    const size_t WFL = 968384;

    size_t avail_fl = ws_size / 4;
    size_t buf_fl = (avail_fl > WFL) ? (avail_fl - WFL) : 0;
    int Cs = (int)(buf_fl / (2 * (size_t)REG));
    if (Cs < 1) Cs = 1;
    if (Cs > 1728) Cs = 1728;
    float* bufA = ws + WFL;
    float* bufB = bufA + (size_t)Cs * REG;

    auto g1 = [](int t) { return (t + 255) / 256; };

    // Weight repacks (once per call)
    repack_k<<<g1(288),    256, 0, stream>>>(Wl[1], bl[1], gl[1], bel[1], ml[1], vl[1], wr1, t1, 1,  9,  32);
    repack_k<<<g1(9216),   256, 0, stream>>>(Wl[2], bl[2], gl[2], bel[2], ml[2], vl[2], wr2, t2, 32, 9,  32);
    repack_k<<<g1(9216),   256, 0, stream>>>(Wl[3], bl[3], gl[3], bel[3], ml[3], vl[3], wr3, t3, 32, 9,  32);
    repack_k<<<g1(9216),   256, 0, stream>>>(Wl[4], bl[4], gl[4], bel[4], ml[4], vl[4], wr4, t4, 32, 9,  32);
    repack_k<<<g1(18432),  256, 0, stream>>>(Wl[5], bl[5], gl[5], bel[5], ml[5], vl[5], wr5, t5, 32, 9,  64);
    repack_k<<<g1(36864),  256, 0, stream>>>(Wl[6], bl[6], gl[6], bel[6], ml[6], vl[6], wr6, t6, 64, 9,  64);
    repack_k<<<g1(884736), 256, 0, stream>>>(Wl[7], bl[7], gl[7], bel[7], ml[7], vl[7], wr7, t7, 64, 108, 128);

    for (int c0 = 0; c0 < 1728; c0 += Cs) {
        int cn = (1728 - c0 < Cs) ? (1728 - c0) : Cs;
        zero_rings_k<<<g1(cn * 20992), 256, 0, stream>>>(bufA, bufB, cn);
        conv1_k<<<g1(cn * 2160), 256, 0, stream>>>(x, bufA, wr1, t1, c0, cn);
        // L2: 32->32 SAME on padded (146,20) -> padded
        convk<32, 32, 20, 2920, 144, 15, 20, 2920, 1, 4, 24, false>
            <<<dim3(6, cn), 192, 0, stream>>>(bufA, bufB, wr2, t2);
        // L3
        convk<32, 32, 20, 2920, 144, 15, 20, 2920, 1, 4, 24, false>
            <<<dim3(6, cn), 192, 0, stream>>>(bufB, bufA, wr3, t3);
        // L4 + pool -> (32,72,16) tight
        convk<32, 32, 20, 2920, 144, 15, 16, 1152, 0, 4, 24, true>
            <<<dim3(6, cn), 192, 0, stream>>>(bufA, bufB, wr4, t4);
        // L5 VALID: (32,72,16) -> (64,70,16)
        convk<32, 64, 16, 1152, 70, 13, 16, 1120, 0, 8, 16, false>
            <<<dim3(5, cn), 256, 0, stream>>>(bufB, bufA, wr5, t5);
        // L6 VALID + pool: (64,70,16) -> (64,34,12)
        convk<64, 64, 16, 1120, 68, 11, 12, 408, 0, 8, 16, true>
            <<<dim3(5, cn), 256, 0, stream>>>(bufA, bufB, wr6, t6);
        // L7 partials: (64,34,12) -> 2 ci-half partial sums, 4 blocks/sample
        conv7p_k<<<dim3(cn, 4), 256, 0, stream>>>(bufB, bufA, wr7);
        // bias + relu + spatial mean
        combine_k<<<g1(cn * 128), 256, 0, stream>>>(bufA, bufB, t7, cn);
        logits_k<<<g1(cn * 25), 256, 0, stream>>>(bufB, W8, b8, (float*)d_out, c0, cn);
    }
}

// Round 5
// 12764.097 us; speedup vs baseline: 1.5377x; 1.1036x over previous
//
#include <hip/hip_runtime.h>
#include <hip/hip_bf16.h>

// Per-sample slot stride (floats): padded SAME buffer 32ch x 146 x 20
#define REG 93440
// conv6 output elements per sample: 64ch x 34 x 12
#define C6N 26112

__device__ inline float b2f(unsigned short u) {
    union { unsigned int i; float f; } v; v.i = ((unsigned int)u) << 16; return v.f;
}

// ---------------------------------------------------------------------------
// Weight repack: [co][ci][kh][kw] -> [ci][k][co] with BN scale folded in.
// Also emits per-channel shift t[co] = (b-m)*s + be,  s = g*rsqrt(v+eps).
// ---------------------------------------------------------------------------
__global__ void repack_k(const float* __restrict__ W, const float* __restrict__ bb,
                         const float* __restrict__ gg, const float* __restrict__ be,
                         const float* __restrict__ mm, const float* __restrict__ vv,
                         float* __restrict__ wOut, float* __restrict__ tOut,
                         int CIN, int KHW, int COUT)
{
    int gid = blockIdx.x * 256 + threadIdx.x;
    if (gid < COUT) {
        float s = gg[gid] * rsqrtf(vv[gid] + 1e-5f);
        tOut[gid] = (bb[gid] - mm[gid]) * s + be[gid];
    }
    int tot = CIN * KHW * COUT;
    if (gid >= tot) return;
    int co = gid % COUT;
    int rest = gid / COUT;       // ci*KHW + k
    int k = rest % KHW;
    int ci = rest / KHW;
    float s = gg[co] * rsqrtf(vv[co] + 1e-5f);
    wOut[gid] = W[(co * CIN + ci) * KHW + k] * s;
}

// ---------------------------------------------------------------------------
// Zero the pad rings of both padded ping-pong buffers.
// ---------------------------------------------------------------------------
__global__ void zero_rings_k(float* __restrict__ bufA, float* __restrict__ bufB, int cn)
{
    int gid = blockIdx.x * 256 + threadIdx.x;
    int tot = cn * 2 * 32 * 328;
    if (gid >= tot) return;
    int e = gid % 328;
    int rest = gid / 328;
    int ch = rest % 32; rest /= 32;
    int bsel = rest & 1;
    int nl = rest >> 1;
    float* base = (bsel ? bufB : bufA) + (size_t)nl * REG + ch * 2920;
    int row, col;
    if (e < 40) { row = (e < 20) ? 0 : 145; col = (e < 20) ? e : e - 20; }
    else { int e2 = e - 40; row = 1 + (e2 >> 1); col = (e2 & 1) ? 16 : 0; }
    base[row * 20 + col] = 0.f;
}

// ---------------------------------------------------------------------------
// Conv1: 1 -> 32 channels, 3x3 SAME, input built on the fly from x windows.
// Two distinct zero paddings on the window axis: conv SAME pad at cols -1/15
// (always zero) and the T-padding (zero when t+c-7 outside [0,108)).
// ---------------------------------------------------------------------------
__global__ __launch_bounds__(256) void conv1_k(
    const float* __restrict__ x, float* __restrict__ out,
    const float* __restrict__ wr, const float* __restrict__ tv,
    int c0, int cn)
{
    int gid = blockIdx.x * 256 + threadIdx.x;
    if (gid >= cn * 2160) return;
    int nl = gid / 2160, p = gid - nl * 2160;
    int f = p / 15, w = p - f * 15;
    int n = c0 + nl;
    int b = n / 108, t = n - b * 108;

    float acc[32];
#pragma unroll
    for (int i = 0; i < 32; ++i) acc[i] = 0.f;

    for (int kh = 0; kh < 3; ++kh) {
        int ff = f + kh - 1;
        if (ff < 0 || ff >= 144) continue;
        for (int kw = 0; kw < 3; ++kw) {
            int c = w + kw - 1;
            if (c < 0 || c >= 15) continue;
            int tt = t + c - 7;
            if (tt < 0 || tt >= 108) continue;
            float xval = x[(b * 108 + tt) * 144 + ff];
            const float* wp = wr + (kh * 3 + kw) * 32;
#pragma unroll
            for (int q = 0; q < 8; ++q) {
                float4 wv = *(const float4*)(wp + q * 4);
                acc[q * 4 + 0] = fmaf(xval, wv.x, acc[q * 4 + 0]);
                acc[q * 4 + 1] = fmaf(xval, wv.y, acc[q * 4 + 1]);
                acc[q * 4 + 2] = fmaf(xval, wv.z, acc[q * 4 + 2]);
                acc[q * 4 + 3] = fmaf(xval, wv.w, acc[q * 4 + 3]);
            }
        }
    }
    float* ob = out + (size_t)nl * REG + (f + 1) * 20 + (w + 1);
#pragma unroll
    for (int co = 0; co < 32; ++co)
        ob[co * 2920] = fmaxf(acc[co] + tv[co], 0.f);
}

// ---------------------------------------------------------------------------
// Generic 3x3 conv (+optional fused 2x1 maxpool over rows, optional bf16 out).
// Thread micro-tile: 8 cout x 8 adjacent cols (w0 in {0,8}), one row.
// ---------------------------------------------------------------------------
template<int CIN, int COUT, int IWS, int ICH, int OH, int OW,
         int OIWS, int OCH, int OOFF, int CG, int ROWS, bool POOL,
         int OSTR, bool BF16O>
__global__ __launch_bounds__(CG * 2 * ROWS) void convk(
    const float* __restrict__ in, void* __restrict__ out,
    const float* __restrict__ wr, const float* __restrict__ tv)
{
    constexpr int CGS = (CG == 4) ? 2 : 3;
    const int tid = threadIdx.x;
    const int cg = tid & (CG - 1);
    const int wh = (tid >> CGS) & 1;
    const int row = tid >> (CGS + 1);
    const int r = blockIdx.x * ROWS + row;
    const int n = blockIdx.y;
    const int w0 = wh ? 8 : 0;
    const float* inN = in + (size_t)n * REG;

    float acc[8][8];
#pragma unroll
    for (int a = 0; a < 8; ++a)
#pragma unroll
        for (int b2 = 0; b2 < 8; ++b2) acc[a][b2] = 0.f;

    for (int ci = 0; ci < CIN; ++ci) {
        const float* ip = inN + ci * ICH + r * IWS + w0;
#pragma unroll
        for (int kh = 0; kh < 3; ++kh) {
            const float4* p4 = (const float4*)(ip + kh * IWS);
            float4 A = p4[0], Bv = p4[1], Cv = p4[2];
            float xv[12] = {A.x, A.y, A.z, A.w, Bv.x, Bv.y, Bv.z, Bv.w,
                            Cv.x, Cv.y, Cv.z, Cv.w};
            const float* wp = wr + ((ci * 3 + kh) * 3) * COUT + cg * 8;
#pragma unroll
            for (int kw = 0; kw < 3; ++kw) {
                float4 wA = *(const float4*)(wp + kw * COUT);
                float4 wB = *(const float4*)(wp + kw * COUT + 4);
#pragma unroll
                for (int j = 0; j < 8; ++j) {
                    float xx = xv[j + kw];
                    acc[0][j] = fmaf(xx, wA.x, acc[0][j]);
                    acc[1][j] = fmaf(xx, wA.y, acc[1][j]);
                    acc[2][j] = fmaf(xx, wA.z, acc[2][j]);
                    acc[3][j] = fmaf(xx, wA.w, acc[3][j]);
                    acc[4][j] = fmaf(xx, wB.x, acc[4][j]);
                    acc[5][j] = fmaf(xx, wB.y, acc[5][j]);
                    acc[6][j] = fmaf(xx, wB.z, acc[6][j]);
                    acc[7][j] = fmaf(xx, wB.w, acc[7][j]);
                }
            }
        }
    }

    const int orow = POOL ? (r >> 1) : r;
#pragma unroll
    for (int co = 0; co < 8; ++co) {
        const int coa = cg * 8 + co;
        const float tb = tv[coa];
        const size_t off = (size_t)n * OSTR + coa * OCH
                         + (orow + OOFF) * OIWS + (w0 + OOFF);
#pragma unroll
        for (int j = 0; j < 8; ++j) {
            float vv = fmaxf(acc[co][j] + tb, 0.f);
            if (POOL) {
                float o = __shfl_xor(vv, CG * 2);
                vv = fmaxf(vv, o);
            }
            bool st = (r < OH) && (w0 + j < OW);
            if (POOL) st = st && ((r & 1) == 0);
            if (st) {
                if constexpr (BF16O)
                    ((__hip_bfloat16*)out)[off + j] = __float2bfloat16(vv);
                else
                    ((float*)out)[off + j] = vv;
            }
        }
    }
}

// ---------------------------------------------------------------------------
// Conv7 over ALL samples in one launch: 64 -> 128 ch, 12x9 VALID on (34,11),
// one block per sample (grid 1728 ~ 6.75 blocks/CU). R2-proven inner: full
// 128 couts per block (cg=tid&15 -> sequential full 512B weight rows; any
// split that re-streams weights lost 1.4-2.7x in R3/R4). Input is bf16
// (halves fetch), staged to fp32 LDS in 16-ch quarters (26KB). Fused
// epilogue: bias+relu+spatial-mean -> pooled[n][128] (LDS-aliased reduce).
// ---------------------------------------------------------------------------
__global__ __launch_bounds__(256) void conv7all_k(
    const unsigned short* __restrict__ c6, float* __restrict__ pooled,
    const float* __restrict__ wr, const float* __restrict__ tv)
{
    __shared__ __align__(16) float sIn[6528];  // 16ch x 34 x 12 = 26KB
    const int n = blockIdx.x;
    const int tid = threadIdx.x;
    const int cg = tid & 15, pg = tid >> 4;

    int base[5]; bool val[5];
#pragma unroll
    for (int i = 0; i < 5; ++i) {
        int p = pg + 16 * i;
        val[i] = p < 69;
        int pc = val[i] ? p : 0;
        int h = pc / 3, w = pc - h * 3;
        base[i] = h * 12 + w;
    }
    float acc[5][8];
#pragma unroll
    for (int i = 0; i < 5; ++i)
#pragma unroll
        for (int c = 0; c < 8; ++c) acc[i][c] = 0.f;

    const ushort4* g4 = (const ushort4*)(c6 + (size_t)n * C6N);
    for (int quar = 0; quar < 4; ++quar) {
        __syncthreads();
        float4* s4 = (float4*)sIn;
        for (int i = tid; i < 1632; i += 256) {
            ushort4 u = g4[quar * 1632 + i];
            float4 f = { b2f(u.x), b2f(u.y), b2f(u.z), b2f(u.w) };
            s4[i] = f;
        }
        __syncthreads();
        for (int cil = 0; cil < 16; ++cil) {
            int ci = quar * 16 + cil;
            const float* sc = sIn + cil * 408;
            const float* wpc = wr + (size_t)ci * 13824 + cg * 8;  // 108*128
            for (int kh = 0; kh < 12; ++kh) {
                const float* sch = sc + kh * 12;
                const float* wph = wpc + kh * 1152;  // 9*128
#pragma unroll
                for (int kw = 0; kw < 9; ++kw) {
                    float4 wA = *(const float4*)(wph + kw * 128);
                    float4 wB = *(const float4*)(wph + kw * 128 + 4);
#pragma unroll
                    for (int i = 0; i < 5; ++i) {
                        float xx = sch[base[i] + kw];
                        acc[i][0] = fmaf(xx, wA.x, acc[i][0]);
                        acc[i][1] = fmaf(xx, wA.y, acc[i][1]);
                        acc[i][2] = fmaf(xx, wA.z, acc[i][2]);
                        acc[i][3] = fmaf(xx, wA.w, acc[i][3]);
                        acc[i][4] = fmaf(xx, wB.x, acc[i][4]);
                        acc[i][5] = fmaf(xx, wB.y, acc[i][5]);
                        acc[i][6] = fmaf(xx, wB.z, acc[i][6]);
                        acc[i][7] = fmaf(xx, wB.w, acc[i][7]);
                    }
                }
            }
        }
    }

    // Fused bias + ReLU + spatial mean. Reuse sIn storage for the reduction.
    __syncthreads();
    float* sP = sIn;  // 16 x 128 floats (8KB) aliased into sIn
#pragma unroll
    for (int co = 0; co < 8; ++co) {
        int coa = cg * 8 + co;
        float tb = tv[coa];
        float s = 0.f;
#pragma unroll
        for (int i = 0; i < 5; ++i)
            if (val[i]) s += fmaxf(acc[i][co] + tb, 0.f);
        sP[pg * 128 + coa] = s;
    }
    __syncthreads();
    if (tid < 128) {
        float s = 0.f;
#pragma unroll
        for (int r = 0; r < 16; ++r) s += sP[r * 128 + tid];
        pooled[(size_t)n * 128 + tid] = s * (1.f / 69.f);
    }
}

// ---------------------------------------------------------------------------
// logits = b8 + W8(25x128) . pooled  (1x1 conv commuted past the mean)
// ---------------------------------------------------------------------------
__global__ void logits_k(const float* __restrict__ pooled, const float* __restrict__ W8,
                         const float* __restrict__ b8, float* __restrict__ outg,
                         int total)
{
    int gid = blockIdx.x * 256 + threadIdx.x;
    if (gid >= total * 25) return;
    int nl = gid / 25, c = gid - nl * 25;
    const float* pp = pooled + (size_t)nl * 128;
    const float* wp = W8 + c * 128;
    float s = b8[c];
#pragma unroll
    for (int ci = 0; ci < 128; ci += 4) {
        float4 wv = *(const float4*)(wp + ci);
        float4 pv = *(const float4*)(pp + ci);
        s = fmaf(wv.x, pv.x, s);
        s = fmaf(wv.y, pv.y, s);
        s = fmaf(wv.z, pv.z, s);
        s = fmaf(wv.w, pv.w, s);
    }
    outg[(size_t)nl * 25 + c] = s;
}

// ---------------------------------------------------------------------------
extern "C" void kernel_launch(void* const* d_in, const int* in_sizes, int n_in,
                              void* d_out, int out_size, void* d_ws, size_t ws_size,
                              hipStream_t stream)
{
    const float* x = (const float*)d_in[0];
    const float* Wl[8]; const float* bl[8]; const float* gl[8];
    const float* bel[8]; const float* ml[8]; const float* vl[8];
    for (int i = 1; i <= 7; ++i) {
        int o = 2 + (i - 1) * 6;
        Wl[i]  = (const float*)d_in[o + 0];
        bl[i]  = (const float*)d_in[o + 1];
        gl[i]  = (const float*)d_in[o + 2];
        bel[i] = (const float*)d_in[o + 3];
        ml[i]  = (const float*)d_in[o + 4];
        vl[i]  = (const float*)d_in[o + 5];
    }
    const float* W8 = (const float*)d_in[44];
    const float* b8 = (const float*)d_in[45];
    float* ws = (float*)d_ws;

    // Workspace layout (float offsets); all 16B aligned.
    float* wr1 = ws + 0;     float* t1 = ws + 288;
    float* wr2 = ws + 320;   float* t2 = ws + 9536;
    float* wr3 = ws + 9568;  float* t3 = ws + 18784;
    float* wr4 = ws + 18816; float* t4 = ws + 28032;
    float* wr5 = ws + 28064; float* t5 = ws + 46496;
    float* wr6 = ws + 46560; float* t6 = ws + 83424;
    float* wr7 = ws + 83488; float* t7 = ws + 968224;
    const size_t WFL = 968384;

    // Persistent regions: conv6 out (bf16, all samples) + pooled.
    unsigned short* c6buf = (unsigned short*)(ws + WFL);
    const size_t C6FL = (size_t)1728 * C6N / 2;       // bf16 elems in float units
    float* pooled = ws + WFL + C6FL;
    const size_t FIXED = WFL + C6FL + (size_t)1728 * 128;

    size_t avail_fl = ws_size / 4;
    size_t buf_fl = (avail_fl > FIXED) ? (avail_fl - FIXED) : 0;
    int Cs = (int)(buf_fl / (2 * (size_t)REG));
    if (Cs < 1) Cs = 1;
    if (Cs > 1728) Cs = 1728;
    float* bufA = ws + FIXED;
    float* bufB = bufA + (size_t)Cs * REG;

    auto g1 = [](int t) { return (t + 255) / 256; };

    // Weight repacks (once per call)
    repack_k<<<g1(288),    256, 0, stream>>>(Wl[1], bl[1], gl[1], bel[1], ml[1], vl[1], wr1, t1, 1,  9,  32);
    repack_k<<<g1(9216),   256, 0, stream>>>(Wl[2], bl[2], gl[2], bel[2], ml[2], vl[2], wr2, t2, 32, 9,  32);
    repack_k<<<g1(9216),   256, 0, stream>>>(Wl[3], bl[3], gl[3], bel[3], ml[3], vl[3], wr3, t3, 32, 9,  32);
    repack_k<<<g1(9216),   256, 0, stream>>>(Wl[4], bl[4], gl[4], bel[4], ml[4], vl[4], wr4, t4, 32, 9,  32);
    repack_k<<<g1(18432),  256, 0, stream>>>(Wl[5], bl[5], gl[5], bel[5], ml[5], vl[5], wr5, t5, 32, 9,  64);
    repack_k<<<g1(36864),  256, 0, stream>>>(Wl[6], bl[6], gl[6], bel[6], ml[6], vl[6], wr6, t6, 64, 9,  64);
    repack_k<<<g1(884736), 256, 0, stream>>>(Wl[7], bl[7], gl[7], bel[7], ml[7], vl[7], wr7, t7, 64, 108, 128);

    // Stage 1 (chunked): conv1..conv6, conv6 -> persistent bf16
    for (int c0 = 0; c0 < 1728; c0 += Cs) {
        int cn = (1728 - c0 < Cs) ? (1728 - c0) : Cs;
        zero_rings_k<<<g1(cn * 20992), 256, 0, stream>>>(bufA, bufB, cn);
        conv1_k<<<g1(cn * 2160), 256, 0, stream>>>(x, bufA, wr1, t1, c0, cn);
        convk<32, 32, 20, 2920, 144, 15, 20, 2920, 1, 4, 24, false, REG, false>
            <<<dim3(6, cn), 192, 0, stream>>>(bufA, bufB, wr2, t2);
        convk<32, 32, 20, 2920, 144, 15, 20, 2920, 1, 4, 24, false, REG, false>
            <<<dim3(6, cn), 192, 0, stream>>>(bufB, bufA, wr3, t3);
        convk<32, 32, 20, 2920, 144, 15, 16, 1152, 0, 4, 24, true, REG, false>
            <<<dim3(6, cn), 192, 0, stream>>>(bufA, bufB, wr4, t4);
        convk<32, 64, 16, 1152, 70, 13, 16, 1120, 0, 8, 16, false, REG, false>
            <<<dim3(5, cn), 256, 0, stream>>>(bufB, bufA, wr5, t5);
        // L6 + pool -> persistent bf16 (64,34,12), per-sample stride C6N
        convk<64, 64, 16, 1120, 68, 11, 12, 408, 0, 8, 16, true, C6N, true>
            <<<dim3(5, cn), 256, 0, stream>>>(bufA, c6buf + (size_t)c0 * C6N, wr6, t6);
    }

    // Stage 2: conv7 (+bias+relu+mean) over all samples, then logits.
    conv7all_k<<<1728, 256, 0, stream>>>(c6buf, pooled, wr7, t7);
    logits_k<<<g1(1728 * 25), 256, 0, stream>>>(pooled, W8, b8, (float*)d_out, 1728);
}

// Round 6
// 10818.720 us; speedup vs baseline: 1.8142x; 1.1798x over previous
//
#include <hip/hip_runtime.h>
#include <hip/hip_bf16.h>
#include <hip/hip_fp16.h>

// Per-sample slot stride in HALVES (fp16): padded SAME buffer 32ch x 146 x 20
#define REGH 93440
// conv6 output elements per sample: 64ch x 34 x 12
#define C6N 26112

__device__ inline float h2f(unsigned short u) {
    union { unsigned short s; _Float16 h; } v; v.s = u; return (float)v.h;
}
__device__ inline unsigned short f2h(float f) {
    union { unsigned short s; _Float16 h; } v; v.h = (_Float16)f; return v.s;
}

// ---------------------------------------------------------------------------
// Weight repack: [co][ci][kh][kw] -> [ci][k][co] with BN scale folded in.
// Also emits per-channel shift t[co] = (b-m)*s + be,  s = g*rsqrt(v+eps).
// ---------------------------------------------------------------------------
__global__ void repack_k(const float* __restrict__ W, const float* __restrict__ bb,
                         const float* __restrict__ gg, const float* __restrict__ be,
                         const float* __restrict__ mm, const float* __restrict__ vv,
                         float* __restrict__ wOut, float* __restrict__ tOut,
                         int CIN, int KHW, int COUT)
{
    int gid = blockIdx.x * 256 + threadIdx.x;
    if (gid < COUT) {
        float s = gg[gid] * rsqrtf(vv[gid] + 1e-5f);
        tOut[gid] = (bb[gid] - mm[gid]) * s + be[gid];
    }
    int tot = CIN * KHW * COUT;
    if (gid >= tot) return;
    int co = gid % COUT;
    int rest = gid / COUT;       // ci*KHW + k
    int k = rest % KHW;
    int ci = rest / KHW;
    float s = gg[co] * rsqrtf(vv[co] + 1e-5f);
    wOut[gid] = W[(co * CIN + ci) * KHW + k] * s;
}

// ---------------------------------------------------------------------------
// Zero the pad rings of both padded ping-pong buffers (fp16).
// ---------------------------------------------------------------------------
__global__ void zero_rings_k(unsigned short* __restrict__ bufA,
                             unsigned short* __restrict__ bufB, int cn)
{
    int gid = blockIdx.x * 256 + threadIdx.x;
    int tot = cn * 2 * 32 * 328;
    if (gid >= tot) return;
    int e = gid % 328;
    int rest = gid / 328;
    int ch = rest % 32; rest /= 32;
    int bsel = rest & 1;
    int nl = rest >> 1;
    unsigned short* base = (bsel ? bufB : bufA) + (size_t)nl * REGH + ch * 2920;
    int row, col;
    if (e < 40) { row = (e < 20) ? 0 : 145; col = (e < 20) ? e : e - 20; }
    else { int e2 = e - 40; row = 1 + (e2 >> 1); col = (e2 & 1) ? 16 : 0; }
    base[row * 20 + col] = 0;   // fp16 +0.0
}

// ---------------------------------------------------------------------------
// Conv1: 1 -> 32 channels, 3x3 SAME, input built on the fly from x windows.
// Two distinct zero paddings on the window axis: conv SAME pad at cols -1/15
// (always zero) and the T-padding (zero when t+c-7 outside [0,108)).
// ---------------------------------------------------------------------------
__global__ __launch_bounds__(256) void conv1_k(
    const float* __restrict__ x, unsigned short* __restrict__ out,
    const float* __restrict__ wr, const float* __restrict__ tv,
    int c0, int cn)
{
    int gid = blockIdx.x * 256 + threadIdx.x;
    if (gid >= cn * 2160) return;
    int nl = gid / 2160, p = gid - nl * 2160;
    int f = p / 15, w = p - f * 15;
    int n = c0 + nl;
    int b = n / 108, t = n - b * 108;

    float acc[32];
#pragma unroll
    for (int i = 0; i < 32; ++i) acc[i] = 0.f;

    for (int kh = 0; kh < 3; ++kh) {
        int ff = f + kh - 1;
        if (ff < 0 || ff >= 144) continue;
        for (int kw = 0; kw < 3; ++kw) {
            int c = w + kw - 1;
            if (c < 0 || c >= 15) continue;
            int tt = t + c - 7;
            if (tt < 0 || tt >= 108) continue;
            float xval = x[(b * 108 + tt) * 144 + ff];
            const float* wp = wr + (kh * 3 + kw) * 32;
#pragma unroll
            for (int q = 0; q < 8; ++q) {
                float4 wv = *(const float4*)(wp + q * 4);
                acc[q * 4 + 0] = fmaf(xval, wv.x, acc[q * 4 + 0]);
                acc[q * 4 + 1] = fmaf(xval, wv.y, acc[q * 4 + 1]);
                acc[q * 4 + 2] = fmaf(xval, wv.z, acc[q * 4 + 2]);
                acc[q * 4 + 3] = fmaf(xval, wv.w, acc[q * 4 + 3]);
            }
        }
    }
    unsigned short* ob = out + (size_t)nl * REGH + (f + 1) * 20 + (w + 1);
#pragma unroll
    for (int co = 0; co < 32; ++co)
        ob[co * 2920] = f2h(fmaxf(acc[co] + tv[co], 0.f));
}

// ---------------------------------------------------------------------------
// Generic 3x3 conv (+optional fused 2x1 maxpool over rows), fp16 in/out,
// fp32 weights/accum. Thread micro-tile: 8 cout x 8 adjacent cols, one row.
// Input loads: 3x ushort4 (8B, aligned) per (ci,kh); 12 cvt per 192 FMAs.
// ---------------------------------------------------------------------------
template<int CIN, int COUT, int IWS, int ICH, int OH, int OW,
         int OIWS, int OCH, int OOFF, int CG, int ROWS, bool POOL, int OSTR>
__global__ __launch_bounds__(CG * 2 * ROWS) void convk(
    const unsigned short* __restrict__ in, unsigned short* __restrict__ out,
    const float* __restrict__ wr, const float* __restrict__ tv)
{
    constexpr int CGS = (CG == 4) ? 2 : 3;
    const int tid = threadIdx.x;
    const int cg = tid & (CG - 1);
    const int wh = (tid >> CGS) & 1;
    const int row = tid >> (CGS + 1);
    const int r = blockIdx.x * ROWS + row;
    const int n = blockIdx.y;
    const int w0 = wh ? 8 : 0;
    const unsigned short* inN = in + (size_t)n * REGH;

    float acc[8][8];
#pragma unroll
    for (int a = 0; a < 8; ++a)
#pragma unroll
        for (int b2 = 0; b2 < 8; ++b2) acc[a][b2] = 0.f;

    for (int ci = 0; ci < CIN; ++ci) {
        const unsigned short* ip = inN + ci * ICH + r * IWS + w0;
#pragma unroll
        for (int kh = 0; kh < 3; ++kh) {
            const ushort4* p4 = (const ushort4*)(ip + kh * IWS);
            ushort4 A = p4[0], Bv = p4[1], Cv = p4[2];
            float xv[12] = {h2f(A.x), h2f(A.y), h2f(A.z), h2f(A.w),
                            h2f(Bv.x), h2f(Bv.y), h2f(Bv.z), h2f(Bv.w),
                            h2f(Cv.x), h2f(Cv.y), h2f(Cv.z), h2f(Cv.w)};
            const float* wp = wr + ((ci * 3 + kh) * 3) * COUT + cg * 8;
#pragma unroll
            for (int kw = 0; kw < 3; ++kw) {
                float4 wA = *(const float4*)(wp + kw * COUT);
                float4 wB = *(const float4*)(wp + kw * COUT + 4);
#pragma unroll
                for (int j = 0; j < 8; ++j) {
                    float xx = xv[j + kw];
                    acc[0][j] = fmaf(xx, wA.x, acc[0][j]);
                    acc[1][j] = fmaf(xx, wA.y, acc[1][j]);
                    acc[2][j] = fmaf(xx, wA.z, acc[2][j]);
                    acc[3][j] = fmaf(xx, wA.w, acc[3][j]);
                    acc[4][j] = fmaf(xx, wB.x, acc[4][j]);
                    acc[5][j] = fmaf(xx, wB.y, acc[5][j]);
                    acc[6][j] = fmaf(xx, wB.z, acc[6][j]);
                    acc[7][j] = fmaf(xx, wB.w, acc[7][j]);
                }
            }
        }
    }

    const int orow = POOL ? (r >> 1) : r;
#pragma unroll
    for (int co = 0; co < 8; ++co) {
        const int coa = cg * 8 + co;
        const float tb = tv[coa];
        const size_t off = (size_t)n * OSTR + coa * OCH
                         + (orow + OOFF) * OIWS + (w0 + OOFF);
#pragma unroll
        for (int j = 0; j < 8; ++j) {
            float vv = fmaxf(acc[co][j] + tb, 0.f);
            if (POOL) {
                float o = __shfl_xor(vv, CG * 2);
                vv = fmaxf(vv, o);
            }
            bool st = (r < OH) && (w0 + j < OW);
            if (POOL) st = st && ((r & 1) == 0);
            if (st) out[off + j] = f2h(vv);
        }
    }
}

// ---------------------------------------------------------------------------
// Conv7 over ALL samples in one launch: 64 -> 128 ch, 12x9 VALID on (34,11),
// one block per sample. Full 128 couts per block (cg=tid&15 -> sequential
// full 512B weight rows; any split that re-streams weights lost in R3/R4).
// fp16 input staged to fp32 LDS in 16-ch quarters (26KB). Fused epilogue:
// bias+relu+spatial-mean -> pooled[n][128].
// ---------------------------------------------------------------------------
__global__ __launch_bounds__(256) void conv7all_k(
    const unsigned short* __restrict__ c6, float* __restrict__ pooled,
    const float* __restrict__ wr, const float* __restrict__ tv)
{
    __shared__ __align__(16) float sIn[6528];  // 16ch x 34 x 12 = 26KB
    const int n = blockIdx.x;
    const int tid = threadIdx.x;
    const int cg = tid & 15, pg = tid >> 4;

    int base[5]; bool val[5];
#pragma unroll
    for (int i = 0; i < 5; ++i) {
        int p = pg + 16 * i;
        val[i] = p < 69;
        int pc = val[i] ? p : 0;
        int h = pc / 3, w = pc - h * 3;
        base[i] = h * 12 + w;
    }
    float acc[5][8];
#pragma unroll
    for (int i = 0; i < 5; ++i)
#pragma unroll
        for (int c = 0; c < 8; ++c) acc[i][c] = 0.f;

    const ushort4* g4 = (const ushort4*)(c6 + (size_t)n * C6N);
    for (int quar = 0; quar < 4; ++quar) {
        __syncthreads();
        float4* s4 = (float4*)sIn;
        for (int i = tid; i < 1632; i += 256) {
            ushort4 u = g4[quar * 1632 + i];
            float4 f = { h2f(u.x), h2f(u.y), h2f(u.z), h2f(u.w) };
            s4[i] = f;
        }
        __syncthreads();
        for (int cil = 0; cil < 16; ++cil) {
            int ci = quar * 16 + cil;
            const float* sc = sIn + cil * 408;
            const float* wpc = wr + (size_t)ci * 13824 + cg * 8;  // 108*128
            for (int kh = 0; kh < 12; ++kh) {
                const float* sch = sc + kh * 12;
                const float* wph = wpc + kh * 1152;  // 9*128
#pragma unroll
                for (int kw = 0; kw < 9; ++kw) {
                    float4 wA = *(const float4*)(wph + kw * 128);
                    float4 wB = *(const float4*)(wph + kw * 128 + 4);
#pragma unroll
                    for (int i = 0; i < 5; ++i) {
                        float xx = sch[base[i] + kw];
                        acc[i][0] = fmaf(xx, wA.x, acc[i][0]);
                        acc[i][1] = fmaf(xx, wA.y, acc[i][1]);
                        acc[i][2] = fmaf(xx, wA.z, acc[i][2]);
                        acc[i][3] = fmaf(xx, wA.w, acc[i][3]);
                        acc[i][4] = fmaf(xx, wB.x, acc[i][4]);
                        acc[i][5] = fmaf(xx, wB.y, acc[i][5]);
                        acc[i][6] = fmaf(xx, wB.z, acc[i][6]);
                        acc[i][7] = fmaf(xx, wB.w, acc[i][7]);
                    }
                }
            }
        }
    }

    // Fused bias + ReLU + spatial mean. Reuse sIn storage for the reduction.
    __syncthreads();
    float* sP = sIn;  // 16 x 128 floats (8KB) aliased into sIn
#pragma unroll
    for (int co = 0; co < 8; ++co) {
        int coa = cg * 8 + co;
        float tb = tv[coa];
        float s = 0.f;
#pragma unroll
        for (int i = 0; i < 5; ++i)
            if (val[i]) s += fmaxf(acc[i][co] + tb, 0.f);
        sP[pg * 128 + coa] = s;
    }
    __syncthreads();
    if (tid < 128) {
        float s = 0.f;
#pragma unroll
        for (int r = 0; r < 16; ++r) s += sP[r * 128 + tid];
        pooled[(size_t)n * 128 + tid] = s * (1.f / 69.f);
    }
}

// ---------------------------------------------------------------------------
// logits = b8 + W8(25x128) . pooled  (1x1 conv commuted past the mean)
// ---------------------------------------------------------------------------
__global__ void logits_k(const float* __restrict__ pooled, const float* __restrict__ W8,
                         const float* __restrict__ b8, float* __restrict__ outg,
                         int total)
{
    int gid = blockIdx.x * 256 + threadIdx.x;
    if (gid >= total * 25) return;
    int nl = gid / 25, c = gid - nl * 25;
    const float* pp = pooled + (size_t)nl * 128;
    const float* wp = W8 + c * 128;
    float s = b8[c];
#pragma unroll
    for (int ci = 0; ci < 128; ci += 4) {
        float4 wv = *(const float4*)(wp + ci);
        float4 pv = *(const float4*)(pp + ci);
        s = fmaf(wv.x, pv.x, s);
        s = fmaf(wv.y, pv.y, s);
        s = fmaf(wv.z, pv.z, s);
        s = fmaf(wv.w, pv.w, s);
    }
    outg[(size_t)nl * 25 + c] = s;
}

// ---------------------------------------------------------------------------
extern "C" void kernel_launch(void* const* d_in, const int* in_sizes, int n_in,
                              void* d_out, int out_size, void* d_ws, size_t ws_size,
                              hipStream_t stream)
{
    const float* x = (const float*)d_in[0];
    const float* Wl[8]; const float* bl[8]; const float* gl[8];
    const float* bel[8]; const float* ml[8]; const float* vl[8];
    for (int i = 1; i <= 7; ++i) {
        int o = 2 + (i - 1) * 6;
        Wl[i]  = (const float*)d_in[o + 0];
        bl[i]  = (const float*)d_in[o + 1];
        gl[i]  = (const float*)d_in[o + 2];
        bel[i] = (const float*)d_in[o + 3];
        ml[i]  = (const float*)d_in[o + 4];
        vl[i]  = (const float*)d_in[o + 5];
    }
    const float* W8 = (const float*)d_in[44];
    const float* b8 = (const float*)d_in[45];
    float* ws = (float*)d_ws;

    // Workspace layout (float offsets); all 16B aligned.
    float* wr1 = ws + 0;     float* t1 = ws + 288;
    float* wr2 = ws + 320;   float* t2 = ws + 9536;
    float* wr3 = ws + 9568;  float* t3 = ws + 18784;
    float* wr4 = ws + 18816; float* t4 = ws + 28032;
    float* wr5 = ws + 28064; float* t5 = ws + 46496;
    float* wr6 = ws + 46560; float* t6 = ws + 83424;
    float* wr7 = ws + 83488; float* t7 = ws + 968224;
    const size_t WFL = 968384;

    // Persistent: c6 (fp16, all samples) + pooled (fp32).
    unsigned short* c6buf = (unsigned short*)(ws + WFL);
    const size_t C6FL = (size_t)1728 * C6N / 2;       // c6 halves in float units
    float* pooled = ws + WFL + C6FL;
    const size_t FIXED = WFL + C6FL + (size_t)1728 * 128;

    size_t avail_fl = ws_size / 4;
    size_t buf_halves = (avail_fl > FIXED) ? (avail_fl - FIXED) * 2 : 0;
    int Cs = (int)(buf_halves / (2 * (size_t)REGH));
    if (Cs < 1) Cs = 1;
    if (Cs > 1728) Cs = 1728;
    unsigned short* bufA = (unsigned short*)(ws + FIXED);
    unsigned short* bufB = bufA + (size_t)Cs * REGH;

    auto g1 = [](int t) { return (t + 255) / 256; };

    // Weight repacks (once per call)
    repack_k<<<g1(288),    256, 0, stream>>>(Wl[1], bl[1], gl[1], bel[1], ml[1], vl[1], wr1, t1, 1,  9,  32);
    repack_k<<<g1(9216),   256, 0, stream>>>(Wl[2], bl[2], gl[2], bel[2], ml[2], vl[2], wr2, t2, 32, 9,  32);
    repack_k<<<g1(9216),   256, 0, stream>>>(Wl[3], bl[3], gl[3], bel[3], ml[3], vl[3], wr3, t3, 32, 9,  32);
    repack_k<<<g1(9216),   256, 0, stream>>>(Wl[4], bl[4], gl[4], bel[4], ml[4], vl[4], wr4, t4, 32, 9,  32);
    repack_k<<<g1(18432),  256, 0, stream>>>(Wl[5], bl[5], gl[5], bel[5], ml[5], vl[5], wr5, t5, 32, 9,  64);
    repack_k<<<g1(36864),  256, 0, stream>>>(Wl[6], bl[6], gl[6], bel[6], ml[6], vl[6], wr6, t6, 64, 9,  64);
    repack_k<<<g1(884736), 256, 0, stream>>>(Wl[7], bl[7], gl[7], bel[7], ml[7], vl[7], wr7, t7, 64, 108, 128);

    // Stage 1 (chunked): conv1..conv6, fp16 activations; conv6 -> persistent c6
    for (int c0 = 0; c0 < 1728; c0 += Cs) {
        int cn = (1728 - c0 < Cs) ? (1728 - c0) : Cs;
        zero_rings_k<<<g1(cn * 20992), 256, 0, stream>>>(bufA, bufB, cn);
        conv1_k<<<g1(cn * 2160), 256, 0, stream>>>(x, bufA, wr1, t1, c0, cn);
        convk<32, 32, 20, 2920, 144, 15, 20, 2920, 1, 4, 24, false, REGH>
            <<<dim3(6, cn), 192, 0, stream>>>(bufA, bufB, wr2, t2);
        convk<32, 32, 20, 2920, 144, 15, 20, 2920, 1, 4, 24, false, REGH>
            <<<dim3(6, cn), 192, 0, stream>>>(bufB, bufA, wr3, t3);
        convk<32, 32, 20, 2920, 144, 15, 16, 1152, 0, 4, 24, true, REGH>
            <<<dim3(6, cn), 192, 0, stream>>>(bufA, bufB, wr4, t4);
        convk<32, 64, 16, 1152, 70, 13, 16, 1120, 0, 8, 16, false, REGH>
            <<<dim3(5, cn), 256, 0, stream>>>(bufB, bufA, wr5, t5);
        convk<64, 64, 16, 1120, 68, 11, 12, 408, 0, 8, 16, true, C6N>
            <<<dim3(5, cn), 256, 0, stream>>>(bufA, c6buf + (size_t)c0 * C6N, wr6, t6);
    }

    // Stage 2: conv7 (+bias+relu+mean) over all samples, then logits.
    conv7all_k<<<1728, 256, 0, stream>>>(c6buf, pooled, wr7, t7);
    logits_k<<<g1(1728 * 25), 256, 0, stream>>>(pooled, W8, b8, (float*)d_out, 1728);
}

// Round 7
// 8600.697 us; speedup vs baseline: 2.2820x; 1.2579x over previous
//
#include <hip/hip_runtime.h>
#include <hip/hip_bf16.h>
#include <hip/hip_fp16.h>

// Per-sample slot stride in HALVES (fp16): padded SAME buffer 32ch x 146 x 20
#define REGH 93440
// conv6 output halves per sample: [8 cgroups][408 pos][8 ci] fp16
#define C6N 26112

typedef _Float16 v8h __attribute__((ext_vector_type(8)));
typedef float v4f __attribute__((ext_vector_type(4)));
typedef unsigned short u16x8 __attribute__((ext_vector_type(8)));

__device__ inline float h2f(unsigned short u) {
    union { unsigned short s; _Float16 h; } v; v.s = u; return (float)v.h;
}
__device__ inline unsigned short f2h(float f) {
    union { unsigned short s; _Float16 h; } v; v.h = (_Float16)f; return v.s;
}

// ---------------------------------------------------------------------------
// Weight repack (layers 1-6): [co][ci][kh][kw] -> [ci][k][co], BN scale folded.
// Also emits per-channel shift t[co] = (b-m)*s + be,  s = g*rsqrt(v+eps).
// ---------------------------------------------------------------------------
__global__ void repack_k(const float* __restrict__ W, const float* __restrict__ bb,
                         const float* __restrict__ gg, const float* __restrict__ be,
                         const float* __restrict__ mm, const float* __restrict__ vv,
                         float* __restrict__ wOut, float* __restrict__ tOut,
                         int CIN, int KHW, int COUT)
{
    int gid = blockIdx.x * 256 + threadIdx.x;
    if (gid < COUT) {
        float s = gg[gid] * rsqrtf(vv[gid] + 1e-5f);
        tOut[gid] = (bb[gid] - mm[gid]) * s + be[gid];
    }
    int tot = CIN * KHW * COUT;
    if (gid >= tot) return;
    int co = gid % COUT;
    int rest = gid / COUT;       // ci*KHW + k
    int k = rest % KHW;
    int ci = rest / KHW;
    float s = gg[co] * rsqrtf(vv[co] + 1e-5f);
    wOut[gid] = W[(co * CIN + ci) * KHW + k] * s;
}

// ---------------------------------------------------------------------------
// Conv7 weight repack into MFMA B-fragment order, fp16.
// k' ordering: k = (khw, half, kcil) with ci = half*32 + kcil, kcil = quad*8+j.
// frag[(((khw*2 + half)*8 + nt)*64 + lane)*8 + j], lane = (kcil>>3)*16 + (co&15),
// nt = co>>4. B[k][n]: lane holds n = lane&15, k = quad*8+j (16B contiguous).
// Also emits t7.
// ---------------------------------------------------------------------------
__global__ void repack7_k(const float* __restrict__ W, const float* __restrict__ bb,
                          const float* __restrict__ gg, const float* __restrict__ be,
                          const float* __restrict__ mm, const float* __restrict__ vv,
                          unsigned short* __restrict__ frag, float* __restrict__ tOut)
{
    int gid = blockIdx.x * 256 + threadIdx.x;
    if (gid < 128) {
        float s = gg[gid] * rsqrtf(vv[gid] + 1e-5f);
        tOut[gid] = (bb[gid] - mm[gid]) * s + be[gid];
    }
    if (gid >= 884736) return;           // 108*2*8*64*8
    int j    = gid & 7;
    int lane = (gid >> 3) & 63;
    int nt   = (gid >> 9) & 7;
    int half = (gid >> 12) & 1;
    int khw  = gid >> 13;
    int quad = lane >> 4;
    int n    = lane & 15;
    int co   = nt * 16 + n;
    int ci   = half * 32 + quad * 8 + j;
    int kh   = khw / 9, kw = khw - kh * 9;
    float s = gg[co] * rsqrtf(vv[co] + 1e-5f);
    float w = W[((co * 64 + ci) * 12 + kh) * 9 + kw] * s;
    frag[gid] = f2h(w);
}

// ---------------------------------------------------------------------------
// Zero the pad rings of both padded ping-pong buffers (fp16).
// ---------------------------------------------------------------------------
__global__ void zero_rings_k(unsigned short* __restrict__ bufA,
                             unsigned short* __restrict__ bufB, int cn)
{
    int gid = blockIdx.x * 256 + threadIdx.x;
    int tot = cn * 2 * 32 * 328;
    if (gid >= tot) return;
    int e = gid % 328;
    int rest = gid / 328;
    int ch = rest % 32; rest /= 32;
    int bsel = rest & 1;
    int nl = rest >> 1;
    unsigned short* base = (bsel ? bufB : bufA) + (size_t)nl * REGH + ch * 2920;
    int row, col;
    if (e < 40) { row = (e < 20) ? 0 : 145; col = (e < 20) ? e : e - 20; }
    else { int e2 = e - 40; row = 1 + (e2 >> 1); col = (e2 & 1) ? 16 : 0; }
    base[row * 20 + col] = 0;   // fp16 +0.0
}

// ---------------------------------------------------------------------------
// Conv1: 1 -> 32 channels, 3x3 SAME. Two zero paddings on the window axis:
// conv SAME pad at cols -1/15 (always zero) and the T-padding.
// ---------------------------------------------------------------------------
__global__ __launch_bounds__(256) void conv1_k(
    const float* __restrict__ x, unsigned short* __restrict__ out,
    const float* __restrict__ wr, const float* __restrict__ tv,
    int c0, int cn)
{
    int gid = blockIdx.x * 256 + threadIdx.x;
    if (gid >= cn * 2160) return;
    int nl = gid / 2160, p = gid - nl * 2160;
    int f = p / 15, w = p - f * 15;
    int n = c0 + nl;
    int b = n / 108, t = n - b * 108;

    float acc[32];
#pragma unroll
    for (int i = 0; i < 32; ++i) acc[i] = 0.f;

    for (int kh = 0; kh < 3; ++kh) {
        int ff = f + kh - 1;
        if (ff < 0 || ff >= 144) continue;
        for (int kw = 0; kw < 3; ++kw) {
            int c = w + kw - 1;
            if (c < 0 || c >= 15) continue;
            int tt = t + c - 7;
            if (tt < 0 || tt >= 108) continue;
            float xval = x[(b * 108 + tt) * 144 + ff];
            const float* wp = wr + (kh * 3 + kw) * 32;
#pragma unroll
            for (int q = 0; q < 8; ++q) {
                float4 wv = *(const float4*)(wp + q * 4);
                acc[q * 4 + 0] = fmaf(xval, wv.x, acc[q * 4 + 0]);
                acc[q * 4 + 1] = fmaf(xval, wv.y, acc[q * 4 + 1]);
                acc[q * 4 + 2] = fmaf(xval, wv.z, acc[q * 4 + 2]);
                acc[q * 4 + 3] = fmaf(xval, wv.w, acc[q * 4 + 3]);
            }
        }
    }
    unsigned short* ob = out + (size_t)nl * REGH + (f + 1) * 20 + (w + 1);
#pragma unroll
    for (int co = 0; co < 32; ++co)
        ob[co * 2920] = f2h(fmaxf(acc[co] + tv[co], 0.f));
}

// ---------------------------------------------------------------------------
// Generic 3x3 conv (+optional fused 2x1 maxpool), fp16 in/out, fp32 w/accum.
// Thread micro-tile: 8 cout x 8 adjacent cols, one row.
// CMINOR: store channel-minor [cg][pos][co%8] (conv7 MFMA A-fragment layout);
// OIWS = row stride in positions, OCH = per-cgroup stride (halves).
// ---------------------------------------------------------------------------
template<int CIN, int COUT, int IWS, int ICH, int OH, int OW,
         int OIWS, int OCH, int OOFF, int CG, int ROWS, bool POOL, int OSTR,
         bool CMINOR>
__global__ __launch_bounds__(CG * 2 * ROWS) void convk(
    const unsigned short* __restrict__ in, unsigned short* __restrict__ out,
    const float* __restrict__ wr, const float* __restrict__ tv)
{
    constexpr int CGS = (CG == 4) ? 2 : 3;
    const int tid = threadIdx.x;
    const int cg = tid & (CG - 1);
    const int wh = (tid >> CGS) & 1;
    const int row = tid >> (CGS + 1);
    const int r = blockIdx.x * ROWS + row;
    const int n = blockIdx.y;
    const int w0 = wh ? 8 : 0;
    const unsigned short* inN = in + (size_t)n * REGH;

    float acc[8][8];
#pragma unroll
    for (int a = 0; a < 8; ++a)
#pragma unroll
        for (int b2 = 0; b2 < 8; ++b2) acc[a][b2] = 0.f;

    for (int ci = 0; ci < CIN; ++ci) {
        const unsigned short* ip = inN + ci * ICH + r * IWS + w0;
#pragma unroll
        for (int kh = 0; kh < 3; ++kh) {
            const ushort4* p4 = (const ushort4*)(ip + kh * IWS);
            ushort4 A = p4[0], Bv = p4[1], Cv = p4[2];
            float xv[12] = {h2f(A.x), h2f(A.y), h2f(A.z), h2f(A.w),
                            h2f(Bv.x), h2f(Bv.y), h2f(Bv.z), h2f(Bv.w),
                            h2f(Cv.x), h2f(Cv.y), h2f(Cv.z), h2f(Cv.w)};
            const float* wp = wr + ((ci * 3 + kh) * 3) * COUT + cg * 8;
#pragma unroll
            for (int kw = 0; kw < 3; ++kw) {
                float4 wA = *(const float4*)(wp + kw * COUT);
                float4 wB = *(const float4*)(wp + kw * COUT + 4);
#pragma unroll
                for (int j = 0; j < 8; ++j) {
                    float xx = xv[j + kw];
                    acc[0][j] = fmaf(xx, wA.x, acc[0][j]);
                    acc[1][j] = fmaf(xx, wA.y, acc[1][j]);
                    acc[2][j] = fmaf(xx, wA.z, acc[2][j]);
                    acc[3][j] = fmaf(xx, wA.w, acc[3][j]);
                    acc[4][j] = fmaf(xx, wB.x, acc[4][j]);
                    acc[5][j] = fmaf(xx, wB.y, acc[5][j]);
                    acc[6][j] = fmaf(xx, wB.z, acc[6][j]);
                    acc[7][j] = fmaf(xx, wB.w, acc[7][j]);
                }
            }
        }
    }

    const int orow = POOL ? (r >> 1) : r;
    if constexpr (CMINOR) {
        float rv[8][8];
#pragma unroll
        for (int co = 0; co < 8; ++co) {
            const float tb = tv[cg * 8 + co];
#pragma unroll
            for (int j = 0; j < 8; ++j) {
                float vv = fmaxf(acc[co][j] + tb, 0.f);
                if (POOL) { float o = __shfl_xor(vv, CG * 2); vv = fmaxf(vv, o); }
                rv[co][j] = vv;
            }
        }
        bool rowok = (r < OH) && (!POOL || ((r & 1) == 0));
        if (rowok) {
            unsigned short* ob = out + (size_t)n * OSTR + cg * OCH;
#pragma unroll
            for (int j = 0; j < 8; ++j) {
                int col = w0 + j;
                if (col < OW) {
                    u16x8 pk;
#pragma unroll
                    for (int co = 0; co < 8; ++co) pk[co] = f2h(rv[co][j]);
                    *(u16x8*)(ob + (orow * OIWS + col) * 8) = pk;
                }
            }
        }
    } else {
#pragma unroll
        for (int co = 0; co < 8; ++co) {
            const int coa = cg * 8 + co;
            const float tb = tv[coa];
            const size_t off = (size_t)n * OSTR + coa * OCH
                             + (orow + OOFF) * OIWS + (w0 + OOFF);
#pragma unroll
            for (int j = 0; j < 8; ++j) {
                float vv = fmaxf(acc[co][j] + tb, 0.f);
                if (POOL) {
                    float o = __shfl_xor(vv, CG * 2);
                    vv = fmaxf(vv, o);
                }
                bool st = (r < OH) && (w0 + j < OW);
                if (POOL) st = st && ((r & 1) == 0);
                if (st) out[off + j] = f2h(vv);
            }
        }
    }
}

// ---------------------------------------------------------------------------
// Conv7 as MFMA GEMM, all samples in one launch. Per sample: M=69 positions
// (padded 80 = 5 tiles), N=128 couts (8 tiles), K=6912 (2 ci-halves x 108 khw,
// 32 k per step). One block/sample, 4 waves; wave w owns N-tiles {w, w+4} x
// all 5 M-tiles (10 v4f accum frags). A: c6 in [cg][pos][8] fp16 -> per-half
// 26KB LDS memcpy; A-frag = 1 ds_read_b128 (A[m=lane&15][k=quad*8+j]).
// B: fragment-preswizzled weights, 1 coalesced 16B/lane global load (L2-res,
// sequential full stream per block -- the R3/R4 lesson). Epilogue: bias+relu+
// mean via C/D (row=quad*4+reg -> pos, col=lane&15 -> co), quad shfl-reduce.
// ---------------------------------------------------------------------------
__global__ __launch_bounds__(256) void conv7mfma_k(
    const unsigned short* __restrict__ c6, float* __restrict__ pooled,
    const unsigned short* __restrict__ frag7, const float* __restrict__ tv)
{
    __shared__ __align__(16) unsigned short sA[13056];  // [4 quads][408 pos][8]
    const int n = blockIdx.x;
    const int tid = threadIdx.x;
    const int wave = tid >> 6;
    const int lane = tid & 63;
    const int m = lane & 15;
    const int quad = lane >> 4;

    int pm[5];
#pragma unroll
    for (int mt = 0; mt < 5; ++mt) {
        int p = mt * 16 + m;
        if (p >= 69) p = 0;                 // clamp; excluded in epilogue
        pm[mt] = (p / 3) * 12 + (p % 3);
    }

    v4f acc[2][5];
#pragma unroll
    for (int t = 0; t < 2; ++t)
#pragma unroll
        for (int mt = 0; mt < 5; ++mt)
            acc[t][mt] = (v4f){0.f, 0.f, 0.f, 0.f};

    for (int half = 0; half < 2; ++half) {
        __syncthreads();
        {
            const float4* src = (const float4*)(c6 + (size_t)n * C6N + half * 13056);
            float4* dst = (float4*)sA;
            for (int i = tid; i < 1632; i += 256) dst[i] = src[i];
        }
        __syncthreads();
        for (int khw = 0; khw < 108; ++khw) {
            const int off = (khw / 9) * 12 + (khw % 9);  // uniform (SGPR)
            v8h a[5];
#pragma unroll
            for (int mt = 0; mt < 5; ++mt)
                a[mt] = *(const v8h*)(sA + (quad * 408 + pm[mt] + off) * 8);
            const unsigned short* bp = frag7
                + ((size_t)(khw * 2 + half) * 8) * 512 + lane * 8;
#pragma unroll
            for (int t = 0; t < 2; ++t) {
                const int nt = wave + t * 4;
                v8h b = *(const v8h*)(bp + nt * 512);
#pragma unroll
                for (int mt = 0; mt < 5; ++mt)
                    acc[t][mt] = __builtin_amdgcn_mfma_f32_16x16x32_f16(
                        a[mt], b, acc[t][mt], 0, 0, 0);
            }
        }
    }

    // Epilogue: bias + relu + mean over the 69 valid positions.
    float s[2] = {0.f, 0.f};
#pragma unroll
    for (int t = 0; t < 2; ++t) {
        const float tb = tv[(wave + t * 4) * 16 + m];
#pragma unroll
        for (int mt = 0; mt < 5; ++mt) {
#pragma unroll
            for (int rr = 0; rr < 4; ++rr) {
                int p = mt * 16 + quad * 4 + rr;
                if (p < 69) s[t] += fmaxf(acc[t][mt][rr] + tb, 0.f);
            }
        }
    }
#pragma unroll
    for (int t = 0; t < 2; ++t) {
        s[t] += __shfl_xor(s[t], 16);
        s[t] += __shfl_xor(s[t], 32);
    }
    if (lane < 16) {
#pragma unroll
        for (int t = 0; t < 2; ++t)
            pooled[(size_t)n * 128 + (wave + t * 4) * 16 + lane] = s[t] * (1.f / 69.f);
    }
}

// ---------------------------------------------------------------------------
// logits = b8 + W8(25x128) . pooled  (1x1 conv commuted past the mean)
// ---------------------------------------------------------------------------
__global__ void logits_k(const float* __restrict__ pooled, const float* __restrict__ W8,
                         const float* __restrict__ b8, float* __restrict__ outg,
                         int total)
{
    int gid = blockIdx.x * 256 + threadIdx.x;
    if (gid >= total * 25) return;
    int nl = gid / 25, c = gid - nl * 25;
    const float* pp = pooled + (size_t)nl * 128;
    const float* wp = W8 + c * 128;
    float s = b8[c];
#pragma unroll
    for (int ci = 0; ci < 128; ci += 4) {
        float4 wv = *(const float4*)(wp + ci);
        float4 pv = *(const float4*)(pp + ci);
        s = fmaf(wv.x, pv.x, s);
        s = fmaf(wv.y, pv.y, s);
        s = fmaf(wv.z, pv.z, s);
        s = fmaf(wv.w, pv.w, s);
    }
    outg[(size_t)nl * 25 + c] = s;
}

// ---------------------------------------------------------------------------
extern "C" void kernel_launch(void* const* d_in, const int* in_sizes, int n_in,
                              void* d_out, int out_size, void* d_ws, size_t ws_size,
                              hipStream_t stream)
{
    const float* x = (const float*)d_in[0];
    const float* Wl[8]; const float* bl[8]; const float* gl[8];
    const float* bel[8]; const float* ml[8]; const float* vl[8];
    for (int i = 1; i <= 7; ++i) {
        int o = 2 + (i - 1) * 6;
        Wl[i]  = (const float*)d_in[o + 0];
        bl[i]  = (const float*)d_in[o + 1];
        gl[i]  = (const float*)d_in[o + 2];
        bel[i] = (const float*)d_in[o + 3];
        ml[i]  = (const float*)d_in[o + 4];
        vl[i]  = (const float*)d_in[o + 5];
    }
    const float* W8 = (const float*)d_in[44];
    const float* b8 = (const float*)d_in[45];
    float* ws = (float*)d_ws;

    // Workspace layout (float offsets); all 16B aligned.
    float* wr1 = ws + 0;     float* t1 = ws + 288;
    float* wr2 = ws + 320;   float* t2 = ws + 9536;
    float* wr3 = ws + 9568;  float* t3 = ws + 18784;
    float* wr4 = ws + 18816; float* t4 = ws + 28032;
    float* wr5 = ws + 28064; float* t5 = ws + 46496;
    float* wr6 = ws + 46560; float* t6 = ws + 83424;
    float* wr7 = ws + 83488; float* t7 = ws + 968224;   // wr7: fp16 frag buffer
    const size_t WFL = 968384;

    // Persistent: c6 ([n][8][408][8] fp16) + pooled (fp32).
    unsigned short* c6buf = (unsigned short*)(ws + WFL);
    const size_t C6FL = (size_t)1728 * C6N / 2;       // c6 halves in float units
    float* pooled = ws + WFL + C6FL;
    const size_t FIXED = WFL + C6FL + (size_t)1728 * 128;

    size_t avail_fl = ws_size / 4;
    size_t buf_halves = (avail_fl > FIXED) ? (avail_fl - FIXED) * 2 : 0;
    int Cs = (int)(buf_halves / (2 * (size_t)REGH));
    if (Cs < 1) Cs = 1;
    if (Cs > 1728) Cs = 1728;
    unsigned short* bufA = (unsigned short*)(ws + FIXED);
    unsigned short* bufB = bufA + (size_t)Cs * REGH;

    auto g1 = [](int t) { return (t + 255) / 256; };

    // Weight repacks (once per call)
    repack_k<<<g1(288),    256, 0, stream>>>(Wl[1], bl[1], gl[1], bel[1], ml[1], vl[1], wr1, t1, 1,  9,  32);
    repack_k<<<g1(9216),   256, 0, stream>>>(Wl[2], bl[2], gl[2], bel[2], ml[2], vl[2], wr2, t2, 32, 9,  32);
    repack_k<<<g1(9216),   256, 0, stream>>>(Wl[3], bl[3], gl[3], bel[3], ml[3], vl[3], wr3, t3, 32, 9,  32);
    repack_k<<<g1(9216),   256, 0, stream>>>(Wl[4], bl[4], gl[4], bel[4], ml[4], vl[4], wr4, t4, 32, 9,  32);
    repack_k<<<g1(18432),  256, 0, stream>>>(Wl[5], bl[5], gl[5], bel[5], ml[5], vl[5], wr5, t5, 32, 9,  64);
    repack_k<<<g1(36864),  256, 0, stream>>>(Wl[6], bl[6], gl[6], bel[6], ml[6], vl[6], wr6, t6, 64, 9,  64);
    repack7_k<<<g1(884736), 256, 0, stream>>>(Wl[7], bl[7], gl[7], bel[7], ml[7], vl[7],
                                              (unsigned short*)wr7, t7);

    // Stage 1 (chunked): conv1..conv6, fp16 activations; conv6 -> persistent c6
    for (int c0 = 0; c0 < 1728; c0 += Cs) {
        int cn = (1728 - c0 < Cs) ? (1728 - c0) : Cs;
        zero_rings_k<<<g1(cn * 20992), 256, 0, stream>>>(bufA, bufB, cn);
        conv1_k<<<g1(cn * 2160), 256, 0, stream>>>(x, bufA, wr1, t1, c0, cn);
        convk<32, 32, 20, 2920, 144, 15, 20, 2920, 1, 4, 24, false, REGH, false>
            <<<dim3(6, cn), 192, 0, stream>>>(bufA, bufB, wr2, t2);
        convk<32, 32, 20, 2920, 144, 15, 20, 2920, 1, 4, 24, false, REGH, false>
            <<<dim3(6, cn), 192, 0, stream>>>(bufB, bufA, wr3, t3);
        convk<32, 32, 20, 2920, 144, 15, 16, 1152, 0, 4, 24, true, REGH, false>
            <<<dim3(6, cn), 192, 0, stream>>>(bufA, bufB, wr4, t4);
        convk<32, 64, 16, 1152, 70, 13, 16, 1120, 0, 8, 16, false, REGH, false>
            <<<dim3(5, cn), 256, 0, stream>>>(bufB, bufA, wr5, t5);
        // L6 + pool -> persistent c6, channel-minor MFMA-friendly layout
        convk<64, 64, 16, 1120, 68, 11, 12, 3264, 0, 8, 16, true, C6N, true>
            <<<dim3(5, cn), 256, 0, stream>>>(bufA, c6buf + (size_t)c0 * C6N, wr6, t6);
    }

    // Stage 2: conv7 MFMA (+bias+relu+mean) over all samples, then logits.
    conv7mfma_k<<<1728, 256, 0, stream>>>(c6buf, pooled, (const unsigned short*)wr7, t7);
    logits_k<<<g1(1728 * 25), 256, 0, stream>>>(pooled, W8, b8, (float*)d_out, 1728);
}

// Round 8
// 1481.070 us; speedup vs baseline: 13.2518x; 5.8071x over previous
//
#include <hip/hip_runtime.h>
#include <hip/hip_bf16.h>
#include <hip/hip_fp16.h>

// Per-sample slot stride in HALVES: channel-minor padded buffer [4cg][146][20][8]
#define REGH 93440
// conv6 output halves per sample: [8 cgroups][408 pos][8 ci] fp16
#define C6N 26112

typedef _Float16 v8h __attribute__((ext_vector_type(8)));
typedef float v4f __attribute__((ext_vector_type(4)));
typedef unsigned short u16x8 __attribute__((ext_vector_type(8)));

__device__ inline float h2f(unsigned short u) {
    union { unsigned short s; _Float16 h; } v; v.s = u; return (float)v.h;
}
__device__ inline unsigned short f2h(float f) {
    union { unsigned short s; _Float16 h; } v; v.h = (_Float16)f; return v.s;
}

// ---------------------------------------------------------------------------
// conv1 weight repack (fp32): [co][1][kh][kw] -> [k][co], BN folded; emits t.
// ---------------------------------------------------------------------------
__global__ void repack_k(const float* __restrict__ W, const float* __restrict__ bb,
                         const float* __restrict__ gg, const float* __restrict__ be,
                         const float* __restrict__ mm, const float* __restrict__ vv,
                         float* __restrict__ wOut, float* __restrict__ tOut,
                         int CIN, int KHW, int COUT)
{
    int gid = blockIdx.x * 256 + threadIdx.x;
    if (gid < COUT) {
        float s = gg[gid] * rsqrtf(vv[gid] + 1e-5f);
        tOut[gid] = (bb[gid] - mm[gid]) * s + be[gid];
    }
    int tot = CIN * KHW * COUT;
    if (gid >= tot) return;
    int co = gid % COUT;
    int rest = gid / COUT;
    int k = rest % KHW;
    int ci = rest / KHW;
    float s = gg[co] * rsqrtf(vv[co] + 1e-5f);
    wOut[gid] = W[(co * CIN + ci) * KHW + k] * s;
}

// ---------------------------------------------------------------------------
// MFMA B-fragment repack for 3x3 layers (conv2..conv6), fp16.
// frag[(((khw*HALVES + half)*NT + nt)*64 + lane)*8 + j]
//   ci = half*32 + (lane>>4)*8 + j ; co = nt*16 + (lane&15) ; kh=khw/3 kw=khw%3
// ---------------------------------------------------------------------------
__global__ void repack_mfma_k(const float* __restrict__ W, const float* __restrict__ bb,
                              const float* __restrict__ gg, const float* __restrict__ be,
                              const float* __restrict__ mm, const float* __restrict__ vv,
                              unsigned short* __restrict__ frag, float* __restrict__ tOut,
                              int CIN, int NT, int HALVES)
{
    int gid = blockIdx.x * 256 + threadIdx.x;
    int COUT = NT * 16;
    if (gid < COUT) {
        float s = gg[gid] * rsqrtf(vv[gid] + 1e-5f);
        tOut[gid] = (bb[gid] - mm[gid]) * s + be[gid];
    }
    int tot = 9 * HALVES * NT * 512;
    if (gid >= tot) return;
    int j    = gid & 7;
    int lane = (gid >> 3) & 63;
    int nt   = (gid >> 9) % NT;
    int rest = (gid >> 9) / NT;
    int half = rest % HALVES;
    int khw  = rest / HALVES;
    int ci   = half * 32 + (lane >> 4) * 8 + j;
    int co   = nt * 16 + (lane & 15);
    int kh   = khw / 3, kw = khw % 3;
    float s = gg[co] * rsqrtf(vv[co] + 1e-5f);
    frag[gid] = f2h(W[((co * CIN + ci) * 3 + kh) * 3 + kw] * s);
}

// ---------------------------------------------------------------------------
// Conv7 weight repack into MFMA B-fragment order (12x9 kernel), fp16.
// ---------------------------------------------------------------------------
__global__ void repack7_k(const float* __restrict__ W, const float* __restrict__ bb,
                          const float* __restrict__ gg, const float* __restrict__ be,
                          const float* __restrict__ mm, const float* __restrict__ vv,
                          unsigned short* __restrict__ frag, float* __restrict__ tOut)
{
    int gid = blockIdx.x * 256 + threadIdx.x;
    if (gid < 128) {
        float s = gg[gid] * rsqrtf(vv[gid] + 1e-5f);
        tOut[gid] = (bb[gid] - mm[gid]) * s + be[gid];
    }
    if (gid >= 884736) return;           // 108*2*8*64*8
    int j    = gid & 7;
    int lane = (gid >> 3) & 63;
    int nt   = (gid >> 9) & 7;
    int half = (gid >> 12) & 1;
    int khw  = gid >> 13;
    int co   = nt * 16 + (lane & 15);
    int ci   = half * 32 + (lane >> 4) * 8 + j;
    int kh   = khw / 9, kw = khw - kh * 9;
    float s = gg[co] * rsqrtf(vv[co] + 1e-5f);
    frag[gid] = f2h(W[((co * 64 + ci) * 12 + kh) * 9 + kw] * s);
}

// ---------------------------------------------------------------------------
// Zero pad rings of both ping-pong buffers, channel-minor layout.
// Rows 0/145 (20 cols) + cols 0,16 (rows 1..144), per cg, u16x8 stores.
// ---------------------------------------------------------------------------
__global__ void zero_rings_k(unsigned short* __restrict__ bufA,
                             unsigned short* __restrict__ bufB, int cn)
{
    int gid = blockIdx.x * 256 + threadIdx.x;
    int tot = cn * 2 * 4 * 328;
    if (gid >= tot) return;
    int e = gid % 328;
    int rest = gid / 328;
    int cg = rest % 4; rest /= 4;
    int bsel = rest & 1;
    int nl = rest >> 1;
    unsigned short* base = (bsel ? bufB : bufA) + (size_t)nl * REGH + cg * 23360;
    int row, col;
    if (e < 40) { row = (e < 20) ? 0 : 145; col = (e < 20) ? e : e - 20; }
    else { int e2 = e - 40; row = 1 + (e2 >> 1); col = (e2 & 1) ? 16 : 0; }
    *(u16x8*)(base + (row * 20 + col) * 8) = (u16x8){0,0,0,0,0,0,0,0};
}

// ---------------------------------------------------------------------------
// Conv1: 1 -> 32 channels, 3x3 SAME, channel-minor padded output.
// Two zero paddings on the window axis: conv SAME pad at cols -1/15 (always
// zero) and the T-padding (zero when t+c-7 outside [0,108)).
// ---------------------------------------------------------------------------
__global__ __launch_bounds__(256) void conv1_k(
    const float* __restrict__ x, unsigned short* __restrict__ out,
    const float* __restrict__ wr, const float* __restrict__ tv,
    int c0, int cn)
{
    int gid = blockIdx.x * 256 + threadIdx.x;
    if (gid >= cn * 2160) return;
    int nl = gid / 2160, p = gid - nl * 2160;
    int f = p / 15, w = p - f * 15;
    int n = c0 + nl;
    int b = n / 108, t = n - b * 108;

    float acc[32];
#pragma unroll
    for (int i = 0; i < 32; ++i) acc[i] = 0.f;

    for (int kh = 0; kh < 3; ++kh) {
        int ff = f + kh - 1;
        if (ff < 0 || ff >= 144) continue;
        for (int kw = 0; kw < 3; ++kw) {
            int c = w + kw - 1;
            if (c < 0 || c >= 15) continue;
            int tt = t + c - 7;
            if (tt < 0 || tt >= 108) continue;
            float xval = x[(b * 108 + tt) * 144 + ff];
            const float* wp = wr + (kh * 3 + kw) * 32;
#pragma unroll
            for (int q = 0; q < 8; ++q) {
                float4 wv = *(const float4*)(wp + q * 4);
                acc[q * 4 + 0] = fmaf(xval, wv.x, acc[q * 4 + 0]);
                acc[q * 4 + 1] = fmaf(xval, wv.y, acc[q * 4 + 1]);
                acc[q * 4 + 2] = fmaf(xval, wv.z, acc[q * 4 + 2]);
                acc[q * 4 + 3] = fmaf(xval, wv.w, acc[q * 4 + 3]);
            }
        }
    }
    unsigned short* ob = out + (size_t)nl * REGH + ((f + 1) * 20 + (w + 1)) * 8;
#pragma unroll
    for (int cg = 0; cg < 4; ++cg) {
        u16x8 pk;
#pragma unroll
        for (int c = 0; c < 8; ++c)
            pk[c] = f2h(fmaxf(acc[cg * 8 + c] + tv[cg * 8 + c], 0.f));
        *(u16x8*)(ob + cg * 23360) = pk;
    }
}

// ---------------------------------------------------------------------------
// conv2/3/4 as MFMA implicit GEMM: 32->32ch 3x3 SAME on 144x15.
// In/out: [4cg][146][20][8] fp16 padded (POOL out: [4cg][72][16][8]).
// Grid (9 bands, cn); 4 waves; wave: 4 M-tiles x 2 N-tiles. K=9 (khw; quad=cg).
// A: 1x16B global read/lane/tile/step (L1-served, uniform shift offsets).
// B: preswizzled frags (18KB, L2-resident). POOL: M ordered (pr,w,s) so pool
// partners are adjacent C/D regs.
// ---------------------------------------------------------------------------
template<bool POOL>
__global__ __launch_bounds__(256) void conv234m_k(
    const unsigned short* __restrict__ in, unsigned short* __restrict__ out,
    const unsigned short* __restrict__ frag, const float* __restrict__ tv)
{
    const int band = blockIdx.x;
    const int n = blockIdx.y;
    const int tid = threadIdx.x;
    const int wave = tid >> 6, lane = tid & 63;
    const int m = lane & 15, quad = lane >> 4;
    const unsigned short* inN = in + (size_t)n * REGH + quad * 23360;

    int mt[4], a0[4];
#pragma unroll
    for (int wt = 0; wt < 4; ++wt) {
        int t = wave * 4 + wt; if (t > 14) t = 14;
        mt[wt] = t;
        int p = band * 240 + t * 16 + m;
        int r, w;
        if (POOL) { int pr = p / 30, rem = p - pr * 30; w = rem >> 1; r = pr * 2 + (rem & 1); }
        else      { r = p / 15; w = p - r * 15; }
        a0[wt] = (r * 20 + w) * 8;
    }

    v4f acc[2][4];
#pragma unroll
    for (int nt = 0; nt < 2; ++nt)
#pragma unroll
        for (int wt = 0; wt < 4; ++wt) acc[nt][wt] = (v4f){0.f,0.f,0.f,0.f};

#pragma unroll
    for (int khw = 0; khw < 9; ++khw) {
        const int shift = ((khw / 3) * 20 + (khw % 3)) * 8;
        v8h a[4];
#pragma unroll
        for (int wt = 0; wt < 4; ++wt)
            a[wt] = *(const v8h*)(inN + a0[wt] + shift);
#pragma unroll
        for (int nt = 0; nt < 2; ++nt) {
            v8h b = *(const v8h*)(frag + (khw * 2 + nt) * 512 + lane * 8);
#pragma unroll
            for (int wt = 0; wt < 4; ++wt)
                acc[nt][wt] = __builtin_amdgcn_mfma_f32_16x16x32_f16(a[wt], b, acc[nt][wt], 0, 0, 0);
        }
    }

    unsigned short* outN = out + (size_t)n * REGH;
#pragma unroll
    for (int wt = 0; wt < 4; ++wt) {
        const int pb = band * 240 + mt[wt] * 16 + quad * 4;
#pragma unroll
        for (int nt = 0; nt < 2; ++nt) {
            const int co = nt * 16 + m;
            const float tb = tv[co];
            unsigned short* ob = outN + (co >> 3) * (POOL ? 9216 : 23360) + (co & 7);
            if (POOL) {
#pragma unroll
                for (int pi = 0; pi < 2; ++pi) {
                    int pe = pb + pi * 2;
                    int pr = pe / 30, rem = pe - pr * 30, w = rem >> 1;
                    float v0 = fmaxf(acc[nt][wt][pi * 2] + tb, 0.f);
                    float v1 = fmaxf(acc[nt][wt][pi * 2 + 1] + tb, 0.f);
                    ob[(pr * 16 + w) * 8] = f2h(fmaxf(v0, v1));
                }
            } else {
#pragma unroll
                for (int reg = 0; reg < 4; ++reg) {
                    int pr = pb + reg;
                    int f = pr / 15, w = pr - f * 15;
                    ob[((f + 1) * 20 + (w + 1)) * 8] = f2h(fmaxf(acc[nt][wt][reg] + tb, 0.f));
                }
            }
        }
    }
}

// ---------------------------------------------------------------------------
// conv5 MFMA: 32->64ch 3x3 VALID, in [4cg][72][16][8] -> out [8cg][70][16][8].
// M=910 (70x13) = 57 tiles; grid (8, cn); wave: 2 M x 4 N. K=9.
// ---------------------------------------------------------------------------
__global__ __launch_bounds__(256) void conv5m_k(
    const unsigned short* __restrict__ in, unsigned short* __restrict__ out,
    const unsigned short* __restrict__ frag, const float* __restrict__ tv)
{
    const int n = blockIdx.y;
    const int tid = threadIdx.x;
    const int wave = tid >> 6, lane = tid & 63;
    const int m = lane & 15, quad = lane >> 4;
    const unsigned short* inN = in + (size_t)n * REGH + quad * 9216;

    int mt[2], a0[2];
#pragma unroll
    for (int wt = 0; wt < 2; ++wt) {
        int t = blockIdx.x * 8 + wave * 2 + wt; if (t > 56) t = 56;
        mt[wt] = t;
        int p = t * 16 + m; if (p > 909) p = 909;
        int r = p / 13, w = p - r * 13;
        a0[wt] = (r * 16 + w) * 8;
    }

    v4f acc[4][2];
#pragma unroll
    for (int nt = 0; nt < 4; ++nt)
#pragma unroll
        for (int wt = 0; wt < 2; ++wt) acc[nt][wt] = (v4f){0.f,0.f,0.f,0.f};

#pragma unroll
    for (int khw = 0; khw < 9; ++khw) {
        const int shift = ((khw / 3) * 16 + (khw % 3)) * 8;
        v8h a[2];
#pragma unroll
        for (int wt = 0; wt < 2; ++wt)
            a[wt] = *(const v8h*)(inN + a0[wt] + shift);
#pragma unroll
        for (int nt = 0; nt < 4; ++nt) {
            v8h b = *(const v8h*)(frag + (khw * 4 + nt) * 512 + lane * 8);
#pragma unroll
            for (int wt = 0; wt < 2; ++wt)
                acc[nt][wt] = __builtin_amdgcn_mfma_f32_16x16x32_f16(a[wt], b, acc[nt][wt], 0, 0, 0);
        }
    }

    unsigned short* outN = out + (size_t)n * REGH;
#pragma unroll
    for (int wt = 0; wt < 2; ++wt) {
        const int pb = mt[wt] * 16 + quad * 4;
#pragma unroll
        for (int nt = 0; nt < 4; ++nt) {
            const int co = nt * 16 + m;
            const float tb = tv[co];
            unsigned short* ob = outN + (co >> 3) * 8960 + (co & 7);
#pragma unroll
            for (int reg = 0; reg < 4; ++reg) {
                int p = pb + reg;
                if (p < 910) {
                    int r = p / 13, w = p - r * 13;
                    ob[(r * 16 + w) * 8] = f2h(fmaxf(acc[nt][wt][reg] + tb, 0.f));
                }
            }
        }
    }
}

// ---------------------------------------------------------------------------
// conv6 MFMA (+fused pool): 64->64ch 3x3 VALID on (70,13) -> (68,11), pool ->
// (34,11) stored into c6 [8cg][408 pos][8]. M=748 ordered (pr,w,s) = pr*22+
// w*2+s so pool partners are adjacent regs; 47 tiles; grid (6, cn);
// wave: 2 M x 4 N; K=18 (9 khw x 2 ci-halves).
// ---------------------------------------------------------------------------
__global__ __launch_bounds__(256) void conv6m_k(
    const unsigned short* __restrict__ in, unsigned short* __restrict__ c6,
    const unsigned short* __restrict__ frag, const float* __restrict__ tv)
{
    const int n = blockIdx.y;
    const int tid = threadIdx.x;
    const int wave = tid >> 6, lane = tid & 63;
    const int m = lane & 15, quad = lane >> 4;
    const unsigned short* inN = in + (size_t)n * REGH;

    int mt[2], a0[2];
#pragma unroll
    for (int wt = 0; wt < 2; ++wt) {
        int t = blockIdx.x * 8 + wave * 2 + wt; if (t > 46) t = 46;
        mt[wt] = t;
        int p = t * 16 + m; if (p > 747) p = 747;
        int pr = p / 22, rem = p - pr * 22;
        int w = rem >> 1, r = pr * 2 + (rem & 1);
        a0[wt] = (r * 16 + w) * 8;
    }

    v4f acc[4][2];
#pragma unroll
    for (int nt = 0; nt < 4; ++nt)
#pragma unroll
        for (int wt = 0; wt < 2; ++wt) acc[nt][wt] = (v4f){0.f,0.f,0.f,0.f};

#pragma unroll
    for (int khw = 0; khw < 9; ++khw) {
        const int shift = ((khw / 3) * 16 + (khw % 3)) * 8;
#pragma unroll
        for (int half = 0; half < 2; ++half) {
            const unsigned short* ip = inN + (half * 4 + quad) * 8960 + shift;
            v8h a[2];
#pragma unroll
            for (int wt = 0; wt < 2; ++wt)
                a[wt] = *(const v8h*)(ip + a0[wt]);
#pragma unroll
            for (int nt = 0; nt < 4; ++nt) {
                v8h b = *(const v8h*)(frag + ((khw * 2 + half) * 4 + nt) * 512 + lane * 8);
#pragma unroll
                for (int wt = 0; wt < 2; ++wt)
                    acc[nt][wt] = __builtin_amdgcn_mfma_f32_16x16x32_f16(a[wt], b, acc[nt][wt], 0, 0, 0);
            }
        }
    }

    unsigned short* outN = c6 + (size_t)n * C6N;
#pragma unroll
    for (int wt = 0; wt < 2; ++wt) {
        const int pb = mt[wt] * 16 + quad * 4;
#pragma unroll
        for (int nt = 0; nt < 4; ++nt) {
            const int co = nt * 16 + m;
            const float tb = tv[co];
            unsigned short* ob = outN + (co >> 3) * 3264 + (co & 7);
#pragma unroll
            for (int pi = 0; pi < 2; ++pi) {
                int pe = pb + pi * 2;
                if (pe < 748) {
                    int pr = pe / 22, rem = pe - pr * 22, w = rem >> 1;
                    float v0 = fmaxf(acc[nt][wt][pi * 2] + tb, 0.f);
                    float v1 = fmaxf(acc[nt][wt][pi * 2 + 1] + tb, 0.f);
                    ob[(pr * 12 + w) * 8] = f2h(fmaxf(v0, v1));
                }
            }
        }
    }
}

// ---------------------------------------------------------------------------
// Conv7 MFMA GEMM over all samples (proven in R7). M=69 pos, N=128, K=6912.
// ---------------------------------------------------------------------------
__global__ __launch_bounds__(256) void conv7mfma_k(
    const unsigned short* __restrict__ c6, float* __restrict__ pooled,
    const unsigned short* __restrict__ frag7, const float* __restrict__ tv)
{
    __shared__ __align__(16) unsigned short sA[13056];
    const int n = blockIdx.x;
    const int tid = threadIdx.x;
    const int wave = tid >> 6;
    const int lane = tid & 63;
    const int m = lane & 15;
    const int quad = lane >> 4;

    int pm[5];
#pragma unroll
    for (int mt = 0; mt < 5; ++mt) {
        int p = mt * 16 + m;
        if (p >= 69) p = 0;
        pm[mt] = (p / 3) * 12 + (p % 3);
    }

    v4f acc[2][5];
#pragma unroll
    for (int t = 0; t < 2; ++t)
#pragma unroll
        for (int mt = 0; mt < 5; ++mt)
            acc[t][mt] = (v4f){0.f, 0.f, 0.f, 0.f};

    for (int half = 0; half < 2; ++half) {
        __syncthreads();
        {
            const float4* src = (const float4*)(c6 + (size_t)n * C6N + half * 13056);
            float4* dst = (float4*)sA;
            for (int i = tid; i < 1632; i += 256) dst[i] = src[i];
        }
        __syncthreads();
        for (int khw = 0; khw < 108; ++khw) {
            const int off = (khw / 9) * 12 + (khw % 9);
            v8h a[5];
#pragma unroll
            for (int mt = 0; mt < 5; ++mt)
                a[mt] = *(const v8h*)(sA + (quad * 408 + pm[mt] + off) * 8);
            const unsigned short* bp = frag7
                + ((size_t)(khw * 2 + half) * 8) * 512 + lane * 8;
#pragma unroll
            for (int t = 0; t < 2; ++t) {
                const int nt = wave + t * 4;
                v8h b = *(const v8h*)(bp + nt * 512);
#pragma unroll
                for (int mt = 0; mt < 5; ++mt)
                    acc[t][mt] = __builtin_amdgcn_mfma_f32_16x16x32_f16(
                        a[mt], b, acc[t][mt], 0, 0, 0);
            }
        }
    }

    float s[2] = {0.f, 0.f};
#pragma unroll
    for (int t = 0; t < 2; ++t) {
        const float tb = tv[(wave + t * 4) * 16 + m];
#pragma unroll
        for (int mt = 0; mt < 5; ++mt) {
#pragma unroll
            for (int rr = 0; rr < 4; ++rr) {
                int p = mt * 16 + quad * 4 + rr;
                if (p < 69) s[t] += fmaxf(acc[t][mt][rr] + tb, 0.f);
            }
        }
    }
#pragma unroll
    for (int t = 0; t < 2; ++t) {
        s[t] += __shfl_xor(s[t], 16);
        s[t] += __shfl_xor(s[t], 32);
    }
    if (lane < 16) {
#pragma unroll
        for (int t = 0; t < 2; ++t)
            pooled[(size_t)n * 128 + (wave + t * 4) * 16 + lane] = s[t] * (1.f / 69.f);
    }
}

// ---------------------------------------------------------------------------
// logits = b8 + W8(25x128) . pooled
// ---------------------------------------------------------------------------
__global__ void logits_k(const float* __restrict__ pooled, const float* __restrict__ W8,
                         const float* __restrict__ b8, float* __restrict__ outg,
                         int total)
{
    int gid = blockIdx.x * 256 + threadIdx.x;
    if (gid >= total * 25) return;
    int nl = gid / 25, c = gid - nl * 25;
    const float* pp = pooled + (size_t)nl * 128;
    const float* wp = W8 + c * 128;
    float s = b8[c];
#pragma unroll
    for (int ci = 0; ci < 128; ci += 4) {
        float4 wv = *(const float4*)(wp + ci);
        float4 pv = *(const float4*)(pp + ci);
        s = fmaf(wv.x, pv.x, s);
        s = fmaf(wv.y, pv.y, s);
        s = fmaf(wv.z, pv.z, s);
        s = fmaf(wv.w, pv.w, s);
    }
    outg[(size_t)nl * 25 + c] = s;
}

// ---------------------------------------------------------------------------
extern "C" void kernel_launch(void* const* d_in, const int* in_sizes, int n_in,
                              void* d_out, int out_size, void* d_ws, size_t ws_size,
                              hipStream_t stream)
{
    const float* x = (const float*)d_in[0];
    const float* Wl[8]; const float* bl[8]; const float* gl[8];
    const float* bel[8]; const float* ml[8]; const float* vl[8];
    for (int i = 1; i <= 7; ++i) {
        int o = 2 + (i - 1) * 6;
        Wl[i]  = (const float*)d_in[o + 0];
        bl[i]  = (const float*)d_in[o + 1];
        gl[i]  = (const float*)d_in[o + 2];
        bel[i] = (const float*)d_in[o + 3];
        ml[i]  = (const float*)d_in[o + 4];
        vl[i]  = (const float*)d_in[o + 5];
    }
    const float* W8 = (const float*)d_in[44];
    const float* b8 = (const float*)d_in[45];
    float* ws = (float*)d_ws;

    // Workspace layout (float offsets); all 16B aligned.
    float* wr1 = ws + 0;        float* t1 = ws + 288;        // fp32, 288
    unsigned short* f2b = (unsigned short*)(ws + 320);       // 9216 h = 4608 fl
    float* t2 = ws + 4928;
    unsigned short* f3b = (unsigned short*)(ws + 4960);
    float* t3 = ws + 9568;
    unsigned short* f4b = (unsigned short*)(ws + 9600);
    float* t4 = ws + 14208;
    unsigned short* f5b = (unsigned short*)(ws + 14240);     // 18432 h = 9216 fl
    float* t5 = ws + 23456;
    unsigned short* f6b = (unsigned short*)(ws + 23520);     // 36864 h = 18432 fl
    float* t6 = ws + 41952;
    unsigned short* f7b = (unsigned short*)(ws + 42016);     // 884736 h = 442368 fl
    float* t7 = ws + 484384;
    const size_t WFL = 484512;

    // Persistent: c6 ([n][8][408][8] fp16) + pooled (fp32).
    unsigned short* c6buf = (unsigned short*)(ws + WFL);
    const size_t C6FL = (size_t)1728 * C6N / 2;
    float* pooled = ws + WFL + C6FL;
    const size_t FIXED = WFL + C6FL + (size_t)1728 * 128;

    size_t avail_fl = ws_size / 4;
    size_t buf_halves = (avail_fl > FIXED) ? (avail_fl - FIXED) * 2 : 0;
    int Cs = (int)(buf_halves / (2 * (size_t)REGH));
    if (Cs < 1) Cs = 1;
    if (Cs > 1728) Cs = 1728;
    unsigned short* bufA = (unsigned short*)(ws + FIXED);
    unsigned short* bufB = bufA + (size_t)Cs * REGH;

    auto g1 = [](int t) { return (t + 255) / 256; };

    // Weight repacks (once per call)
    repack_k<<<g1(288), 256, 0, stream>>>(Wl[1], bl[1], gl[1], bel[1], ml[1], vl[1], wr1, t1, 1, 9, 32);
    repack_mfma_k<<<g1(9216),  256, 0, stream>>>(Wl[2], bl[2], gl[2], bel[2], ml[2], vl[2], f2b, t2, 32, 2, 1);
    repack_mfma_k<<<g1(9216),  256, 0, stream>>>(Wl[3], bl[3], gl[3], bel[3], ml[3], vl[3], f3b, t3, 32, 2, 1);
    repack_mfma_k<<<g1(9216),  256, 0, stream>>>(Wl[4], bl[4], gl[4], bel[4], ml[4], vl[4], f4b, t4, 32, 2, 1);
    repack_mfma_k<<<g1(18432), 256, 0, stream>>>(Wl[5], bl[5], gl[5], bel[5], ml[5], vl[5], f5b, t5, 32, 4, 1);
    repack_mfma_k<<<g1(36864), 256, 0, stream>>>(Wl[6], bl[6], gl[6], bel[6], ml[6], vl[6], f6b, t6, 64, 4, 2);
    repack7_k<<<g1(884736), 256, 0, stream>>>(Wl[7], bl[7], gl[7], bel[7], ml[7], vl[7], f7b, t7);

    // Stage 1 (chunked): conv1..conv6 (all MFMA except conv1)
    for (int c0 = 0; c0 < 1728; c0 += Cs) {
        int cn = (1728 - c0 < Cs) ? (1728 - c0) : Cs;
        zero_rings_k<<<g1(cn * 2624), 256, 0, stream>>>(bufA, bufB, cn);
        conv1_k<<<g1(cn * 2160), 256, 0, stream>>>(x, bufA, wr1, t1, c0, cn);
        conv234m_k<false><<<dim3(9, cn), 256, 0, stream>>>(bufA, bufB, f2b, t2);
        conv234m_k<false><<<dim3(9, cn), 256, 0, stream>>>(bufB, bufA, f3b, t3);
        conv234m_k<true ><<<dim3(9, cn), 256, 0, stream>>>(bufA, bufB, f4b, t4);
        conv5m_k<<<dim3(8, cn), 256, 0, stream>>>(bufB, bufA, f5b, t5);
        conv6m_k<<<dim3(6, cn), 256, 0, stream>>>(bufA, c6buf + (size_t)c0 * C6N, f6b, t6);
    }

    // Stage 2: conv7 MFMA (+bias+relu+mean) over all samples, then logits.
    conv7mfma_k<<<1728, 256, 0, stream>>>(c6buf, pooled, f7b, t7);
    logits_k<<<g1(1728 * 25), 256, 0, stream>>>(pooled, W8, b8, (float*)d_out, 1728);
}

// Round 9
// 1378.621 us; speedup vs baseline: 14.2365x; 1.0743x over previous
//
#include <hip/hip_runtime.h>
#include <hip/hip_bf16.h>
#include <hip/hip_fp16.h>

// Per-sample slot stride in HALVES: channel-minor padded buffer [4cg][146][20][8]
#define REGH 93440
// conv6 output halves per sample: [8 cgroups][408 pos][8 ci] fp16
#define C6N 26112

typedef _Float16 v8h __attribute__((ext_vector_type(8)));
typedef float v4f __attribute__((ext_vector_type(4)));
typedef unsigned short u16x8 __attribute__((ext_vector_type(8)));

__device__ inline float h2f(unsigned short u) {
    union { unsigned short s; _Float16 h; } v; v.s = u; return (float)v.h;
}
__device__ inline unsigned short f2h(float f) {
    union { unsigned short s; _Float16 h; } v; v.h = (_Float16)f; return v.s;
}

// ---------------------------------------------------------------------------
// conv1 weight repack (fp32): [co][1][kh][kw] -> [k][co], BN folded; emits t.
// ---------------------------------------------------------------------------
__global__ void repack_k(const float* __restrict__ W, const float* __restrict__ bb,
                         const float* __restrict__ gg, const float* __restrict__ be,
                         const float* __restrict__ mm, const float* __restrict__ vv,
                         float* __restrict__ wOut, float* __restrict__ tOut,
                         int CIN, int KHW, int COUT)
{
    int gid = blockIdx.x * 256 + threadIdx.x;
    if (gid < COUT) {
        float s = gg[gid] * rsqrtf(vv[gid] + 1e-5f);
        tOut[gid] = (bb[gid] - mm[gid]) * s + be[gid];
    }
    int tot = CIN * KHW * COUT;
    if (gid >= tot) return;
    int co = gid % COUT;
    int rest = gid / COUT;
    int k = rest % KHW;
    int ci = rest / KHW;
    float s = gg[co] * rsqrtf(vv[co] + 1e-5f);
    wOut[gid] = W[(co * CIN + ci) * KHW + k] * s;
}

// ---------------------------------------------------------------------------
// MFMA B-fragment repack for 3x3 layers (conv2..conv6), fp16.
// frag[(((khw*HALVES + half)*NT + nt)*64 + lane)*8 + j]
//   ci = half*32 + (lane>>4)*8 + j ; co = nt*16 + (lane&15) ; kh=khw/3 kw=khw%3
// ---------------------------------------------------------------------------
__global__ void repack_mfma_k(const float* __restrict__ W, const float* __restrict__ bb,
                              const float* __restrict__ gg, const float* __restrict__ be,
                              const float* __restrict__ mm, const float* __restrict__ vv,
                              unsigned short* __restrict__ frag, float* __restrict__ tOut,
                              int CIN, int NT, int HALVES)
{
    int gid = blockIdx.x * 256 + threadIdx.x;
    int COUT = NT * 16;
    if (gid < COUT) {
        float s = gg[gid] * rsqrtf(vv[gid] + 1e-5f);
        tOut[gid] = (bb[gid] - mm[gid]) * s + be[gid];
    }
    int tot = 9 * HALVES * NT * 512;
    if (gid >= tot) return;
    int j    = gid & 7;
    int lane = (gid >> 3) & 63;
    int nt   = (gid >> 9) % NT;
    int rest = (gid >> 9) / NT;
    int half = rest % HALVES;
    int khw  = rest / HALVES;
    int ci   = half * 32 + (lane >> 4) * 8 + j;
    int co   = nt * 16 + (lane & 15);
    int kh   = khw / 3, kw = khw % 3;
    float s = gg[co] * rsqrtf(vv[co] + 1e-5f);
    frag[gid] = f2h(W[((co * CIN + ci) * 3 + kh) * 3 + kw] * s);
}

// ---------------------------------------------------------------------------
// Conv7 weight repack into MFMA B-fragment order (12x9 kernel), fp16.
// ---------------------------------------------------------------------------
__global__ void repack7_k(const float* __restrict__ W, const float* __restrict__ bb,
                          const float* __restrict__ gg, const float* __restrict__ be,
                          const float* __restrict__ mm, const float* __restrict__ vv,
                          unsigned short* __restrict__ frag, float* __restrict__ tOut)
{
    int gid = blockIdx.x * 256 + threadIdx.x;
    if (gid < 128) {
        float s = gg[gid] * rsqrtf(vv[gid] + 1e-5f);
        tOut[gid] = (bb[gid] - mm[gid]) * s + be[gid];
    }
    if (gid >= 884736) return;           // 108*2*8*64*8
    int j    = gid & 7;
    int lane = (gid >> 3) & 63;
    int nt   = (gid >> 9) & 7;
    int half = (gid >> 12) & 1;
    int khw  = gid >> 13;
    int co   = nt * 16 + (lane & 15);
    int ci   = half * 32 + (lane >> 4) * 8 + j;
    int kh   = khw / 9, kw = khw - kh * 9;
    float s = gg[co] * rsqrtf(vv[co] + 1e-5f);
    frag[gid] = f2h(W[((co * 64 + ci) * 12 + kh) * 9 + kw] * s);
}

// ---------------------------------------------------------------------------
// Zero pad rings of both ping-pong buffers, channel-minor layout.
// ---------------------------------------------------------------------------
__global__ void zero_rings_k(unsigned short* __restrict__ bufA,
                             unsigned short* __restrict__ bufB, int cn)
{
    int gid = blockIdx.x * 256 + threadIdx.x;
    int tot = cn * 2 * 4 * 328;
    if (gid >= tot) return;
    int e = gid % 328;
    int rest = gid / 328;
    int cg = rest % 4; rest /= 4;
    int bsel = rest & 1;
    int nl = rest >> 1;
    unsigned short* base = (bsel ? bufB : bufA) + (size_t)nl * REGH + cg * 23360;
    int row, col;
    if (e < 40) { row = (e < 20) ? 0 : 145; col = (e < 20) ? e : e - 20; }
    else { int e2 = e - 40; row = 1 + (e2 >> 1); col = (e2 & 1) ? 16 : 0; }
    *(u16x8*)(base + (row * 20 + col) * 8) = (u16x8){0,0,0,0,0,0,0,0};
}

// ---------------------------------------------------------------------------
// Conv1: 1 -> 32 channels, 3x3 SAME, channel-minor padded output.
// Two zero paddings on the window axis: conv SAME pad at cols -1/15 (always
// zero) and the T-padding (zero when t+c-7 outside [0,108)).
// ---------------------------------------------------------------------------
__global__ __launch_bounds__(256) void conv1_k(
    const float* __restrict__ x, unsigned short* __restrict__ out,
    const float* __restrict__ wr, const float* __restrict__ tv,
    int c0, int cn)
{
    int gid = blockIdx.x * 256 + threadIdx.x;
    if (gid >= cn * 2160) return;
    int nl = gid / 2160, p = gid - nl * 2160;
    int f = p / 15, w = p - f * 15;
    int n = c0 + nl;
    int b = n / 108, t = n - b * 108;

    float acc[32];
#pragma unroll
    for (int i = 0; i < 32; ++i) acc[i] = 0.f;

    for (int kh = 0; kh < 3; ++kh) {
        int ff = f + kh - 1;
        if (ff < 0 || ff >= 144) continue;
        for (int kw = 0; kw < 3; ++kw) {
            int c = w + kw - 1;
            if (c < 0 || c >= 15) continue;
            int tt = t + c - 7;
            if (tt < 0 || tt >= 108) continue;
            float xval = x[(b * 108 + tt) * 144 + ff];
            const float* wp = wr + (kh * 3 + kw) * 32;
#pragma unroll
            for (int q = 0; q < 8; ++q) {
                float4 wv = *(const float4*)(wp + q * 4);
                acc[q * 4 + 0] = fmaf(xval, wv.x, acc[q * 4 + 0]);
                acc[q * 4 + 1] = fmaf(xval, wv.y, acc[q * 4 + 1]);
                acc[q * 4 + 2] = fmaf(xval, wv.z, acc[q * 4 + 2]);
                acc[q * 4 + 3] = fmaf(xval, wv.w, acc[q * 4 + 3]);
            }
        }
    }
    unsigned short* ob = out + (size_t)nl * REGH + ((f + 1) * 20 + (w + 1)) * 8;
#pragma unroll
    for (int cg = 0; cg < 4; ++cg) {
        u16x8 pk;
#pragma unroll
        for (int c = 0; c < 8; ++c)
            pk[c] = f2h(fmaxf(acc[cg * 8 + c] + tv[cg * 8 + c], 0.f));
        *(u16x8*)(ob + cg * 23360) = pk;
    }
}

// ---------------------------------------------------------------------------
// conv2/3/4 as MFMA implicit GEMM: 32->32ch 3x3 SAME on 144x15.
// In/out: [4cg][146][20][8] fp16 padded (POOL out: [4cg][72][16][8]).
// Grid (9 bands, cn); 4 waves; wave: 4 M-tiles x 2 N-tiles. K=9 (khw; quad=cg).
// A: band slab (4 quads x 18 rows x 20 x 8 = 23KB) staged to LDS, quad
// stride 361 pos (=1 mod 8 groups -> no 128B periodicity; R8's global-load
// version was load-latency-paced). A-frag = 1 ds_read_b128.
// B: preswizzled frags (global, L2-resident).
// ---------------------------------------------------------------------------
template<bool POOL>
__global__ __launch_bounds__(256) void conv234m_k(
    const unsigned short* __restrict__ in, unsigned short* __restrict__ out,
    const unsigned short* __restrict__ frag, const float* __restrict__ tv)
{
    __shared__ __align__(16) unsigned short sA[11552];  // 4 x 361 x 8
    const int band = blockIdx.x;
    const int n = blockIdx.y;
    const int tid = threadIdx.x;
    const int wave = tid >> 6, lane = tid & 63;
    const int m = lane & 15, quad = lane >> 4;

    // Stage band slab: rows band*16 .. band*16+17 of each quad.
    {
        const float4* src = (const float4*)(in + (size_t)n * REGH);
        float4* dst = (float4*)sA;
        for (int i = tid; i < 1440; i += 256) {
            int q = i / 360, pos = i - q * 360;
            dst[q * 361 + pos] = src[q * 2920 + band * 320 + pos];
        }
    }
    __syncthreads();

    int mt[4], la0[4];
#pragma unroll
    for (int wt = 0; wt < 4; ++wt) {
        int t = wave * 4 + wt; if (t > 14) t = 14;
        mt[wt] = t;
        int p = band * 240 + t * 16 + m;
        int r, w;
        if (POOL) { int pr = p / 30, rem = p - pr * 30; w = rem >> 1; r = pr * 2 + (rem & 1); }
        else      { r = p / 15; w = p - r * 15; }
        la0[wt] = ((r - band * 16) * 20 + w) * 8;
    }

    v4f acc[2][4];
#pragma unroll
    for (int nt = 0; nt < 2; ++nt)
#pragma unroll
        for (int wt = 0; wt < 4; ++wt) acc[nt][wt] = (v4f){0.f,0.f,0.f,0.f};

    const unsigned short* sQ = sA + quad * 361 * 8;
#pragma unroll
    for (int khw = 0; khw < 9; ++khw) {
        const int shift = ((khw / 3) * 20 + (khw % 3)) * 8;
        v8h a[4];
#pragma unroll
        for (int wt = 0; wt < 4; ++wt)
            a[wt] = *(const v8h*)(sQ + la0[wt] + shift);
#pragma unroll
        for (int nt = 0; nt < 2; ++nt) {
            v8h b = *(const v8h*)(frag + (khw * 2 + nt) * 512 + lane * 8);
#pragma unroll
            for (int wt = 0; wt < 4; ++wt)
                acc[nt][wt] = __builtin_amdgcn_mfma_f32_16x16x32_f16(a[wt], b, acc[nt][wt], 0, 0, 0);
        }
    }

    unsigned short* outN = out + (size_t)n * REGH;
#pragma unroll
    for (int wt = 0; wt < 4; ++wt) {
        const int pb = band * 240 + mt[wt] * 16 + quad * 4;
#pragma unroll
        for (int nt = 0; nt < 2; ++nt) {
            const int co = nt * 16 + m;
            const float tb = tv[co];
            unsigned short* ob = outN + (co >> 3) * (POOL ? 9216 : 23360) + (co & 7);
            if (POOL) {
#pragma unroll
                for (int pi = 0; pi < 2; ++pi) {
                    int pe = pb + pi * 2;
                    int pr = pe / 30, rem = pe - pr * 30, w = rem >> 1;
                    float v0 = fmaxf(acc[nt][wt][pi * 2] + tb, 0.f);
                    float v1 = fmaxf(acc[nt][wt][pi * 2 + 1] + tb, 0.f);
                    ob[(pr * 16 + w) * 8] = f2h(fmaxf(v0, v1));
                }
            } else {
#pragma unroll
                for (int reg = 0; reg < 4; ++reg) {
                    int pr = pb + reg;
                    int f = pr / 15, w = pr - f * 15;
                    ob[((f + 1) * 20 + (w + 1)) * 8] = f2h(fmaxf(acc[nt][wt][reg] + tb, 0.f));
                }
            }
        }
    }
}

// ---------------------------------------------------------------------------
// conv5 MFMA: 32->64ch 3x3 VALID, in [4cg][72][16][8] -> out [8cg][70][16][8].
// M=910 (70x13) = 57 tiles; grid (8, cn); wave: 2 M x 4 N. K=9. (unchanged R8)
// ---------------------------------------------------------------------------
__global__ __launch_bounds__(256) void conv5m_k(
    const unsigned short* __restrict__ in, unsigned short* __restrict__ out,
    const unsigned short* __restrict__ frag, const float* __restrict__ tv)
{
    const int n = blockIdx.y;
    const int tid = threadIdx.x;
    const int wave = tid >> 6, lane = tid & 63;
    const int m = lane & 15, quad = lane >> 4;
    const unsigned short* inN = in + (size_t)n * REGH + quad * 9216;

    int mt[2], a0[2];
#pragma unroll
    for (int wt = 0; wt < 2; ++wt) {
        int t = blockIdx.x * 8 + wave * 2 + wt; if (t > 56) t = 56;
        mt[wt] = t;
        int p = t * 16 + m; if (p > 909) p = 909;
        int r = p / 13, w = p - r * 13;
        a0[wt] = (r * 16 + w) * 8;
    }

    v4f acc[4][2];
#pragma unroll
    for (int nt = 0; nt < 4; ++nt)
#pragma unroll
        for (int wt = 0; wt < 2; ++wt) acc[nt][wt] = (v4f){0.f,0.f,0.f,0.f};

#pragma unroll
    for (int khw = 0; khw < 9; ++khw) {
        const int shift = ((khw / 3) * 16 + (khw % 3)) * 8;
        v8h a[2];
#pragma unroll
        for (int wt = 0; wt < 2; ++wt)
            a[wt] = *(const v8h*)(inN + a0[wt] + shift);
#pragma unroll
        for (int nt = 0; nt < 4; ++nt) {
            v8h b = *(const v8h*)(frag + (khw * 4 + nt) * 512 + lane * 8);
#pragma unroll
            for (int wt = 0; wt < 2; ++wt)
                acc[nt][wt] = __builtin_amdgcn_mfma_f32_16x16x32_f16(a[wt], b, acc[nt][wt], 0, 0, 0);
        }
    }

    unsigned short* outN = out + (size_t)n * REGH;
#pragma unroll
    for (int wt = 0; wt < 2; ++wt) {
        const int pb = mt[wt] * 16 + quad * 4;
#pragma unroll
        for (int nt = 0; nt < 4; ++nt) {
            const int co = nt * 16 + m;
            const float tb = tv[co];
            unsigned short* ob = outN + (co >> 3) * 8960 + (co & 7);
#pragma unroll
            for (int reg = 0; reg < 4; ++reg) {
                int p = pb + reg;
                if (p < 910) {
                    int r = p / 13, w = p - r * 13;
                    ob[(r * 16 + w) * 8] = f2h(fmaxf(acc[nt][wt][reg] + tb, 0.f));
                }
            }
        }
    }
}

// ---------------------------------------------------------------------------
// conv6 MFMA (+fused pool): 64->64ch 3x3 VALID on (70,13) -> (68,11), pool ->
// (34,11) stored into c6 [8cg][408 pos][8]. (unchanged R8)
// ---------------------------------------------------------------------------
__global__ __launch_bounds__(256) void conv6m_k(
    const unsigned short* __restrict__ in, unsigned short* __restrict__ c6,
    const unsigned short* __restrict__ frag, const float* __restrict__ tv)
{
    const int n = blockIdx.y;
    const int tid = threadIdx.x;
    const int wave = tid >> 6, lane = tid & 63;
    const int m = lane & 15, quad = lane >> 4;
    const unsigned short* inN = in + (size_t)n * REGH;

    int mt[2], a0[2];
#pragma unroll
    for (int wt = 0; wt < 2; ++wt) {
        int t = blockIdx.x * 8 + wave * 2 + wt; if (t > 46) t = 46;
        mt[wt] = t;
        int p = t * 16 + m; if (p > 747) p = 747;
        int pr = p / 22, rem = p - pr * 22;
        int w = rem >> 1, r = pr * 2 + (rem & 1);
        a0[wt] = (r * 16 + w) * 8;
    }

    v4f acc[4][2];
#pragma unroll
    for (int nt = 0; nt < 4; ++nt)
#pragma unroll
        for (int wt = 0; wt < 2; ++wt) acc[nt][wt] = (v4f){0.f,0.f,0.f,0.f};

#pragma unroll
    for (int khw = 0; khw < 9; ++khw) {
        const int shift = ((khw / 3) * 16 + (khw % 3)) * 8;
#pragma unroll
        for (int half = 0; half < 2; ++half) {
            const unsigned short* ip = inN + (half * 4 + quad) * 8960 + shift;
            v8h a[2];
#pragma unroll
            for (int wt = 0; wt < 2; ++wt)
                a[wt] = *(const v8h*)(ip + a0[wt]);
#pragma unroll
            for (int nt = 0; nt < 4; ++nt) {
                v8h b = *(const v8h*)(frag + ((khw * 2 + half) * 4 + nt) * 512 + lane * 8);
#pragma unroll
                for (int wt = 0; wt < 2; ++wt)
                    acc[nt][wt] = __builtin_amdgcn_mfma_f32_16x16x32_f16(a[wt], b, acc[nt][wt], 0, 0, 0);
            }
        }
    }

    unsigned short* outN = c6 + (size_t)n * C6N;
#pragma unroll
    for (int wt = 0; wt < 2; ++wt) {
        const int pb = mt[wt] * 16 + quad * 4;
#pragma unroll
        for (int nt = 0; nt < 4; ++nt) {
            const int co = nt * 16 + m;
            const float tb = tv[co];
            unsigned short* ob = outN + (co >> 3) * 3264 + (co & 7);
#pragma unroll
            for (int pi = 0; pi < 2; ++pi) {
                int pe = pb + pi * 2;
                if (pe < 748) {
                    int pr = pe / 22, rem = pe - pr * 22, w = rem >> 1;
                    float v0 = fmaxf(acc[nt][wt][pi * 2] + tb, 0.f);
                    float v1 = fmaxf(acc[nt][wt][pi * 2 + 1] + tb, 0.f);
                    ob[(pr * 12 + w) * 8] = f2h(fmaxf(v0, v1));
                }
            }
        }
    }
}

// ---------------------------------------------------------------------------
// Conv7 MFMA GEMM over all samples. M=69 pos, N=128, K=6912.
// LDS layout bank-fixed vs R8: row stride 13 (12-wide data, (5h+w)%8 near-
// uniform groups), quad stride 443 (=3 mod 8). R8's 408/12 strides gave
// 6528B = 0 mod 128 -> 4-way inter-quad conflict on every A read (5.4e7
// SQ_LDS_BANK_CONFLICT, ~95cyc A-reads vs 48cyc MFMA per step).
// ---------------------------------------------------------------------------
__global__ __launch_bounds__(256) void conv7mfma_k(
    const unsigned short* __restrict__ c6, float* __restrict__ pooled,
    const unsigned short* __restrict__ frag7, const float* __restrict__ tv)
{
    __shared__ __align__(16) unsigned short sA[14176];  // 4 x 443 x 8
    const int n = blockIdx.x;
    const int tid = threadIdx.x;
    const int wave = tid >> 6;
    const int lane = tid & 63;
    const int m = lane & 15;
    const int quad = lane >> 4;

    int pm[5];
#pragma unroll
    for (int mt = 0; mt < 5; ++mt) {
        int p = mt * 16 + m;
        if (p >= 69) p = 0;
        pm[mt] = (p / 3) * 13 + (p % 3);
    }

    v4f acc[2][5];
#pragma unroll
    for (int t = 0; t < 2; ++t)
#pragma unroll
        for (int mt = 0; mt < 5; ++mt)
            acc[t][mt] = (v4f){0.f, 0.f, 0.f, 0.f};

    for (int half = 0; half < 2; ++half) {
        __syncthreads();
        {
            const float4* src = (const float4*)(c6 + (size_t)n * C6N + half * 13056);
            float4* dst = (float4*)sA;
            for (int i = tid; i < 1632; i += 256) {
                int q = i / 408, pos = i - q * 408;
                int h = pos / 12, w = pos - h * 12;
                dst[q * 443 + h * 13 + w] = src[i];
            }
        }
        __syncthreads();
        for (int khw = 0; khw < 108; ++khw) {
            const int off = (khw / 9) * 13 + (khw % 9);
            v8h a[5];
#pragma unroll
            for (int mt = 0; mt < 5; ++mt)
                a[mt] = *(const v8h*)(sA + (quad * 443 + pm[mt] + off) * 8);
            const unsigned short* bp = frag7
                + ((size_t)(khw * 2 + half) * 8) * 512 + lane * 8;
#pragma unroll
            for (int t = 0; t < 2; ++t) {
                const int nt = wave + t * 4;
                v8h b = *(const v8h*)(bp + nt * 512);
#pragma unroll
                for (int mt = 0; mt < 5; ++mt)
                    acc[t][mt] = __builtin_amdgcn_mfma_f32_16x16x32_f16(
                        a[mt], b, acc[t][mt], 0, 0, 0);
            }
        }
    }

    float s[2] = {0.f, 0.f};
#pragma unroll
    for (int t = 0; t < 2; ++t) {
        const float tb = tv[(wave + t * 4) * 16 + m];
#pragma unroll
        for (int mt = 0; mt < 5; ++mt) {
#pragma unroll
            for (int rr = 0; rr < 4; ++rr) {
                int p = mt * 16 + quad * 4 + rr;
                if (p < 69) s[t] += fmaxf(acc[t][mt][rr] + tb, 0.f);
            }
        }
    }
#pragma unroll
    for (int t = 0; t < 2; ++t) {
        s[t] += __shfl_xor(s[t], 16);
        s[t] += __shfl_xor(s[t], 32);
    }
    if (lane < 16) {
#pragma unroll
        for (int t = 0; t < 2; ++t)
            pooled[(size_t)n * 128 + (wave + t * 4) * 16 + lane] = s[t] * (1.f / 69.f);
    }
}

// ---------------------------------------------------------------------------
// logits = b8 + W8(25x128) . pooled
// ---------------------------------------------------------------------------
__global__ void logits_k(const float* __restrict__ pooled, const float* __restrict__ W8,
                         const float* __restrict__ b8, float* __restrict__ outg,
                         int total)
{
    int gid = blockIdx.x * 256 + threadIdx.x;
    if (gid >= total * 25) return;
    int nl = gid / 25, c = gid - nl * 25;
    const float* pp = pooled + (size_t)nl * 128;
    const float* wp = W8 + c * 128;
    float s = b8[c];
#pragma unroll
    for (int ci = 0; ci < 128; ci += 4) {
        float4 wv = *(const float4*)(wp + ci);
        float4 pv = *(const float4*)(pp + ci);
        s = fmaf(wv.x, pv.x, s);
        s = fmaf(wv.y, pv.y, s);
        s = fmaf(wv.z, pv.z, s);
        s = fmaf(wv.w, pv.w, s);
    }
    outg[(size_t)nl * 25 + c] = s;
}

// ---------------------------------------------------------------------------
extern "C" void kernel_launch(void* const* d_in, const int* in_sizes, int n_in,
                              void* d_out, int out_size, void* d_ws, size_t ws_size,
                              hipStream_t stream)
{
    const float* x = (const float*)d_in[0];
    const float* Wl[8]; const float* bl[8]; const float* gl[8];
    const float* bel[8]; const float* ml[8]; const float* vl[8];
    for (int i = 1; i <= 7; ++i) {
        int o = 2 + (i - 1) * 6;
        Wl[i]  = (const float*)d_in[o + 0];
        bl[i]  = (const float*)d_in[o + 1];
        gl[i]  = (const float*)d_in[o + 2];
        bel[i] = (const float*)d_in[o + 3];
        ml[i]  = (const float*)d_in[o + 4];
        vl[i]  = (const float*)d_in[o + 5];
    }
    const float* W8 = (const float*)d_in[44];
    const float* b8 = (const float*)d_in[45];
    float* ws = (float*)d_ws;

    // Workspace layout (float offsets); all 16B aligned.
    float* wr1 = ws + 0;        float* t1 = ws + 288;
    unsigned short* f2b = (unsigned short*)(ws + 320);
    float* t2 = ws + 4928;
    unsigned short* f3b = (unsigned short*)(ws + 4960);
    float* t3 = ws + 9568;
    unsigned short* f4b = (unsigned short*)(ws + 9600);
    float* t4 = ws + 14208;
    unsigned short* f5b = (unsigned short*)(ws + 14240);
    float* t5 = ws + 23456;
    unsigned short* f6b = (unsigned short*)(ws + 23520);
    float* t6 = ws + 41952;
    unsigned short* f7b = (unsigned short*)(ws + 42016);
    float* t7 = ws + 484384;
    const size_t WFL = 484512;

    // Persistent: c6 ([n][8][408][8] fp16) + pooled (fp32).
    unsigned short* c6buf = (unsigned short*)(ws + WFL);
    const size_t C6FL = (size_t)1728 * C6N / 2;
    float* pooled = ws + WFL + C6FL;
    const size_t FIXED = WFL + C6FL + (size_t)1728 * 128;

    size_t avail_fl = ws_size / 4;
    size_t buf_halves = (avail_fl > FIXED) ? (avail_fl - FIXED) * 2 : 0;
    int Cs = (int)(buf_halves / (2 * (size_t)REGH));
    if (Cs < 1) Cs = 1;
    if (Cs > 1728) Cs = 1728;
    unsigned short* bufA = (unsigned short*)(ws + FIXED);
    unsigned short* bufB = bufA + (size_t)Cs * REGH;

    auto g1 = [](int t) { return (t + 255) / 256; };

    // Weight repacks (once per call)
    repack_k<<<g1(288), 256, 0, stream>>>(Wl[1], bl[1], gl[1], bel[1], ml[1], vl[1], wr1, t1, 1, 9, 32);
    repack_mfma_k<<<g1(9216),  256, 0, stream>>>(Wl[2], bl[2], gl[2], bel[2], ml[2], vl[2], f2b, t2, 32, 2, 1);
    repack_mfma_k<<<g1(9216),  256, 0, stream>>>(Wl[3], bl[3], gl[3], bel[3], ml[3], vl[3], f3b, t3, 32, 2, 1);
    repack_mfma_k<<<g1(9216),  256, 0, stream>>>(Wl[4], bl[4], gl[4], bel[4], ml[4], vl[4], f4b, t4, 32, 2, 1);
    repack_mfma_k<<<g1(18432), 256, 0, stream>>>(Wl[5], bl[5], gl[5], bel[5], ml[5], vl[5], f5b, t5, 32, 4, 1);
    repack_mfma_k<<<g1(36864), 256, 0, stream>>>(Wl[6], bl[6], gl[6], bel[6], ml[6], vl[6], f6b, t6, 64, 4, 2);
    repack7_k<<<g1(884736), 256, 0, stream>>>(Wl[7], bl[7], gl[7], bel[7], ml[7], vl[7], f7b, t7);

    // Stage 1 (chunked): conv1..conv6 (all MFMA except conv1)
    for (int c0 = 0; c0 < 1728; c0 += Cs) {
        int cn = (1728 - c0 < Cs) ? (1728 - c0) : Cs;
        zero_rings_k<<<g1(cn * 2624), 256, 0, stream>>>(bufA, bufB, cn);
        conv1_k<<<g1(cn * 2160), 256, 0, stream>>>(x, bufA, wr1, t1, c0, cn);
        conv234m_k<false><<<dim3(9, cn), 256, 0, stream>>>(bufA, bufB, f2b, t2);
        conv234m_k<false><<<dim3(9, cn), 256, 0, stream>>>(bufB, bufA, f3b, t3);
        conv234m_k<true ><<<dim3(9, cn), 256, 0, stream>>>(bufA, bufB, f4b, t4);
        conv5m_k<<<dim3(8, cn), 256, 0, stream>>>(bufB, bufA, f5b, t5);
        conv6m_k<<<dim3(6, cn), 256, 0, stream>>>(bufA, c6buf + (size_t)c0 * C6N, f6b, t6);
    }

    // Stage 2: conv7 MFMA (+bias+relu+mean) over all samples, then logits.
    conv7mfma_k<<<1728, 256, 0, stream>>>(c6buf, pooled, f7b, t7);
    logits_k<<<g1(1728 * 25), 256, 0, stream>>>(pooled, W8, b8, (float*)d_out, 1728);
}